// Round 1
// baseline (1483.977 us; speedup 1.0000x reference)
//
#include <hip/hip_runtime.h>
#include <math.h>

#define BB 8
#define NN 2048
#define NPOINT 102
#define H_REP 0.0005f

// ---------------- init accumulators ----------------
__global__ void k_init(double* acc) {
    int i = threadIdx.x;
    if (i < 48) acc[i] = 0.0;
}

// ---------------- chamfer: per-row min over other cloud ----------------
// A rows vs Bp cols; accumulates sum of per-row min d2 into *slot.
__global__ __launch_bounds__(256) void k_cd(const float* __restrict__ A,
                                            const float* __restrict__ Bp,
                                            double* __restrict__ slot) {
    int b = blockIdx.y;
    __shared__ float4 sB[NN];  // 32 KB
    const float* bb = Bp + (size_t)b * NN * 3;
    for (int j = threadIdx.x; j < NN; j += 256) {
        float x = bb[j * 3 + 0], y = bb[j * 3 + 1], z = bb[j * 3 + 2];
        sB[j] = make_float4(x, y, z, 0.0f);
    }
    __syncthreads();
    int r = blockIdx.x * 256 + threadIdx.x;
    const float* aa = A + ((size_t)b * NN + r) * 3;
    float ax = aa[0], ay = aa[1], az = aa[2];
    float mn = 1e30f;
    for (int j = 0; j < NN; j++) {
        float4 p = sB[j];
        float dx = ax - p.x, dy = ay - p.y, dz = az - p.z;
        float d2 = dx * dx + dy * dy + dz * dz;
        mn = fminf(mn, d2);
    }
    atomicAdd(slot, (double)mn);
}

// ---------------- repulsion: 4 nearest non-self, relu(h - d2) ----------------
__global__ __launch_bounds__(256) void k_rep(const float* __restrict__ pcd,
                                             double* __restrict__ slot) {
    int b = blockIdx.y;
    __shared__ float4 sP[NN];  // 32 KB
    const float* pp = pcd + (size_t)b * NN * 3;
    for (int j = threadIdx.x; j < NN; j += 256) {
        float x = pp[j * 3 + 0], y = pp[j * 3 + 1], z = pp[j * 3 + 2];
        sP[j] = make_float4(x, y, z, 0.0f);
    }
    __syncthreads();
    int i = blockIdx.x * 256 + threadIdx.x;
    float4 q = sP[i];
    float t0 = 1e30f, t1 = 1e30f, t2 = 1e30f, t3 = 1e30f, t4 = 1e30f;
    for (int j = 0; j < NN; j++) {
        float4 p = sP[j];
        float dx = q.x - p.x, dy = q.y - p.y, dz = q.z - p.z;
        float d2 = dx * dx + dy * dy + dz * dz;
        if (d2 < t4) {
            if (d2 < t0)      { t4 = t3; t3 = t2; t2 = t1; t1 = t0; t0 = d2; }
            else if (d2 < t1) { t4 = t3; t3 = t2; t2 = t1; t1 = d2; }
            else if (d2 < t2) { t4 = t3; t3 = t2; t2 = d2; }
            else if (d2 < t3) { t4 = t3; t3 = d2; }
            else              { t4 = d2; }
        }
    }
    float s = fmaxf(H_REP - t1, 0.f) + fmaxf(H_REP - t2, 0.f) +
              fmaxf(H_REP - t3, 0.f) + fmaxf(H_REP - t4, 0.f);
    atomicAdd(slot, (double)s);
}

// ---------------- farthest point sampling (sequential, 1 block/batch) ----------------
__global__ __launch_bounds__(256) void k_fps(const float* __restrict__ pcd,
                                             int* __restrict__ fidx) {
    int b = blockIdx.x;
    __shared__ float sx[NN], sy[NN], sz[NN], dist[NN];
    __shared__ float rv[256];
    __shared__ int ri[256];
    __shared__ int s_last;
    const float* pp = pcd + (size_t)b * NN * 3;
    for (int i = threadIdx.x; i < NN; i += 256) {
        sx[i] = pp[i * 3 + 0];
        sy[i] = pp[i * 3 + 1];
        sz[i] = pp[i * 3 + 2];
        dist[i] = 1e10f;
    }
    if (threadIdx.x == 0) { s_last = 0; fidx[b * NPOINT + 0] = 0; }
    __syncthreads();
    for (int step = 1; step < NPOINT; ++step) {
        int last = s_last;
        float lx = sx[last], ly = sy[last], lz = sz[last];
        float bv = -1.0f;
        int bi = 0;
        for (int i = threadIdx.x; i < NN; i += 256) {
            float dx = sx[i] - lx, dy = sy[i] - ly, dz = sz[i] - lz;
            float d = dx * dx + dy * dy + dz * dz;
            float nd = fminf(dist[i], d);
            dist[i] = nd;
            if (nd > bv) { bv = nd; bi = i; }   // strict > keeps first index per thread
        }
        rv[threadIdx.x] = bv;
        ri[threadIdx.x] = bi;
        __syncthreads();
        for (int off = 128; off > 0; off >>= 1) {
            if (threadIdx.x < off) {
                float v2 = rv[threadIdx.x + off];
                int i2 = ri[threadIdx.x + off];
                float v1 = rv[threadIdx.x];
                int i1 = ri[threadIdx.x];
                if (v2 > v1 || (v2 == v1 && i2 < i1)) {
                    rv[threadIdx.x] = v2;
                    ri[threadIdx.x] = i2;
                }
            }
            __syncthreads();
        }
        if (threadIdx.x == 0) { s_last = ri[0]; fidx[b * NPOINT + step] = ri[0]; }
        __syncthreads();
    }
}

// ---------------- ball query: 1 wave per (batch, center) ----------------
// Collect first nsample indices (ascending) with d2 < r2 (expansion formula,
// matching reference); pad with first selected index.
__global__ __launch_bounds__(64) void k_ball(const float* __restrict__ pcd,
                                             const int* __restrict__ fidx,
                                             int* __restrict__ gidx,
                                             int nsample, float r2) {
    int c = blockIdx.x;
    int b = blockIdx.y;
    int lane = threadIdx.x;
    const float* pp = pcd + (size_t)b * NN * 3;
    int ci = fidx[b * NPOINT + c];
    float cx = pp[ci * 3 + 0], cy = pp[ci * 3 + 1], cz = pp[ci * 3 + 2];
    float sc = cx * cx + cy * cy + cz * cz;
    int* out = gidx + ((size_t)b * NPOINT + c) * nsample;
    int cnt = 0;
    int first = 0;
    for (int j0 = 0; j0 < NN && cnt < nsample; j0 += 64) {
        int j = j0 + lane;
        float x = pp[j * 3 + 0], y = pp[j * 3 + 1], z = pp[j * 3 + 2];
        float sj = x * x + y * y + z * z;
        float d2 = fmaxf(sc + sj - 2.0f * (cx * x + cy * y + cz * z), 0.0f);
        bool pred = d2 < r2;
        unsigned long long mask = __ballot(pred);
        if (cnt == 0 && mask != 0ull) first = j0 + (int)__builtin_ctzll(mask);
        if (pred) {
            int pos = cnt + (int)__popcll(mask & ((1ull << lane) - 1ull));
            if (pos < nsample) out[pos] = j;
        }
        cnt += (int)__popcll(mask);
    }
    if (cnt < nsample) {
        for (int s = cnt + lane; s < nsample; s += 64) out[s] = first;
    }
}

// ---------------- kNN-2 over grouped set; accumulate sqrt(2nd-min)+1e-8 per batch ----------------
__global__ __launch_bounds__(256) void k_uknn(const float* __restrict__ pcd,
                                              const int* __restrict__ gidx,
                                              int nsample, int M,
                                              double* __restrict__ slot) {
    int b = blockIdx.y;
    __shared__ float4 sP[2448];  // max M, 39 KB
    const float* pp = pcd + (size_t)b * NN * 3;
    const int* gb = gidx + (size_t)b * NPOINT * nsample;
    for (int g = threadIdx.x; g < M; g += 256) {
        int id = gb[g];
        float x = pp[id * 3 + 0], y = pp[id * 3 + 1], z = pp[id * 3 + 2];
        sP[g] = make_float4(x, y, z, 0.0f);
    }
    __syncthreads();
    int i = blockIdx.x * 256 + threadIdx.x;
    if (i < M) {
        float4 q = sP[i];
        float m1 = 1e30f, m2 = 1e30f;
        for (int j = 0; j < M; j++) {
            float4 p = sP[j];
            float dx = q.x - p.x, dy = q.y - p.y, dz = q.z - p.z;
            // direct formula: exact 0 for bit-identical duplicates (padding!)
            float d2 = dx * dx + dy * dy + dz * dz;
            if (d2 < m1)      { m2 = m1; m1 = d2; }
            else if (d2 < m2) { m2 = d2; }
        }
        float val = sqrtf(m2) + 1e-8f;
        atomicAdd(slot + b, (double)val);
    }
}

// ---------------- finalize ----------------
__global__ void k_final(const double* __restrict__ acc,
                        const float* __restrict__ radius,
                        float* __restrict__ out) {
    double cd = (0.8 * acc[0] + 0.2 * acc[1]) / ((double)BB * NN) / (double)radius[0];
    double rep = acc[2] / ((double)BB * NN * 4.0);
    const double ps[5] = {0.004, 0.006, 0.008, 0.01, 0.012};
    const int nss[5] = {8, 12, 16, 20, 24};
    double uni = 0.0;
    for (int pi = 0; pi < 5; pi++) {
        double p = ps[pi];
        int M = NPOINT * nss[pi];
        double disk_area = M_PI * 1.0 / (double)NN;
        double e = sqrt(disk_area);
        double bacc = 0.0;
        for (int b = 0; b < BB; b++) {
            double m = acc[3 + pi * 8 + b] / (double)M;
            double d = m - e;
            bacc += d * d / (e + 1e-8);
        }
        uni += (bacc / (double)BB) * (p * 100.0) * (p * 100.0);
    }
    uni /= 5.0;
    out[0] = (float)(cd + rep + uni);
}

extern "C" void kernel_launch(void* const* d_in, const int* in_sizes, int n_in,
                              void* d_out, int out_size, void* d_ws, size_t ws_size,
                              hipStream_t stream) {
    const float* pred = (const float*)d_in[0];
    const float* gt = (const float*)d_in[1];
    const float* radius = (const float*)d_in[2];
    float* out = (float*)d_out;

    double* acc = (double*)d_ws;        // 48 doubles: 0=for 1=bac 2=rep 3..42=uni[5][8]
    int* fidx = (int*)(acc + 48);       // 8*102
    int* gidx = (int*)(fidx + BB * NPOINT);  // up to 8*102*24

    hipLaunchKernelGGL(k_init, dim3(1), dim3(64), 0, stream, acc);
    hipLaunchKernelGGL(k_cd, dim3(NN / 256, BB), dim3(256), 0, stream, gt, pred, acc + 0);
    hipLaunchKernelGGL(k_cd, dim3(NN / 256, BB), dim3(256), 0, stream, pred, gt, acc + 1);
    hipLaunchKernelGGL(k_rep, dim3(NN / 256, BB), dim3(256), 0, stream, pred, acc + 2);
    hipLaunchKernelGGL(k_fps, dim3(BB), dim3(256), 0, stream, pred, fidx);

    const double ps[5] = {0.004, 0.006, 0.008, 0.01, 0.012};
    const int nss[5] = {8, 12, 16, 20, 24};
    for (int pi = 0; pi < 5; pi++) {
        int ns = nss[pi];
        int M = NPOINT * ns;
        float r2 = (float)(sqrt(ps[pi]) * sqrt(ps[pi]));
        hipLaunchKernelGGL(k_ball, dim3(NPOINT, BB), dim3(64), 0, stream,
                           pred, fidx, gidx, ns, r2);
        int nblk = (M + 255) / 256;
        hipLaunchKernelGGL(k_uknn, dim3(nblk, BB), dim3(256), 0, stream,
                           pred, gidx, ns, M, acc + 3 + pi * 8);
    }
    hipLaunchKernelGGL(k_final, dim3(1), dim3(1), 0, stream, acc, radius, out);
}

// Round 2
// 574.084 us; speedup vs baseline: 2.5849x; 2.5849x over previous
//
#include <hip/hip_runtime.h>
#include <math.h>

#define BB 8
#define NN 2048
#define NPOINT 102
#define H_REP 0.0005f

// ---------------- init accumulators ----------------
__global__ void k_init(double* acc) {
    int i = threadIdx.x;
    if (i < 48) acc[i] = 0.0;
}

// ---------------- block sum helper (double) ----------------
template <int NWAVE>
__device__ inline void block_sum_atomic(double v, double* sacc, double* target) {
    for (int off = 32; off; off >>= 1) v += __shfl_down(v, off, 64);
    int lane = threadIdx.x & 63, wid = threadIdx.x >> 6;
    if (lane == 0) sacc[wid] = v;
    __syncthreads();
    if (threadIdx.x == 0) {
        double s = sacc[0];
#pragma unroll
        for (int w = 1; w < NWAVE; w++) s += sacc[w];
        atomicAdd(target, s);
    }
}

// ---------------- chamfer both directions: z=0 rows of gt vs pred, z=1 rows of pred vs gt --------
__global__ __launch_bounds__(128) void k_cd2(const float* __restrict__ pred,
                                             const float* __restrict__ gt,
                                             double* __restrict__ acc) {
    int z = blockIdx.z;
    int b = blockIdx.y;
    const float* A = z ? pred : gt;
    const float* Bp = z ? gt : pred;
    __shared__ float4 sB[NN];  // 32 KB
    __shared__ double sacc[2];
    const float* bb = Bp + (size_t)b * NN * 3;
    for (int j = threadIdx.x; j < NN; j += 128) {
        float x = bb[j * 3 + 0], y = bb[j * 3 + 1], zv = bb[j * 3 + 2];
        sB[j] = make_float4(x, y, zv, 0.0f);
    }
    __syncthreads();
    int r = blockIdx.x * 128 + threadIdx.x;
    const float* aa = A + ((size_t)b * NN + r) * 3;
    float ax = aa[0], ay = aa[1], az = aa[2];
    float mn = 1e30f;
#pragma unroll 8
    for (int j = 0; j < NN; j++) {
        float4 p = sB[j];
        float dx = ax - p.x, dy = ay - p.y, dz = az - p.z;
        float d2 = dx * dx + dy * dy + dz * dz;
        mn = fminf(mn, d2);
    }
    block_sum_atomic<2>((double)mn, sacc, acc + z);
}

// ---------------- repulsion: branchless 5-smallest insert ----------------
__global__ __launch_bounds__(128) void k_rep(const float* __restrict__ pcd,
                                             double* __restrict__ slot) {
    int b = blockIdx.y;
    __shared__ float4 sP[NN];  // 32 KB
    __shared__ double sacc[2];
    const float* pp = pcd + (size_t)b * NN * 3;
    for (int j = threadIdx.x; j < NN; j += 128) {
        float x = pp[j * 3 + 0], y = pp[j * 3 + 1], z = pp[j * 3 + 2];
        sP[j] = make_float4(x, y, z, 0.0f);
    }
    __syncthreads();
    int i = blockIdx.x * 128 + threadIdx.x;
    float4 q = sP[i];
    float t0 = 1e30f, t1 = 1e30f, t2 = 1e30f, t3 = 1e30f, t4 = 1e30f;
#pragma unroll 8
    for (int j = 0; j < NN; j++) {
        float4 p = sP[j];
        float dx = q.x - p.x, dy = q.y - p.y, dz = q.z - p.z;
        float c = dx * dx + dy * dy + dz * dz;
        float lo;
        lo = fminf(t0, c); c = fmaxf(t0, c); t0 = lo;
        lo = fminf(t1, c); c = fmaxf(t1, c); t1 = lo;
        lo = fminf(t2, c); c = fmaxf(t2, c); t2 = lo;
        lo = fminf(t3, c); c = fmaxf(t3, c); t3 = lo;
        t4 = fminf(t4, c);
    }
    float s = fmaxf(H_REP - t1, 0.f) + fmaxf(H_REP - t2, 0.f) +
              fmaxf(H_REP - t3, 0.f) + fmaxf(H_REP - t4, 0.f);
    block_sum_atomic<2>((double)s, sacc, slot);
}

// ---------------- farthest point sampling: points+dist in registers, shuffle argmax ----
__global__ __launch_bounds__(256) void k_fps(const float* __restrict__ pcd,
                                             int* __restrict__ fidx) {
    int b = blockIdx.x;
    int tid = threadIdx.x;
    __shared__ float4 sP[NN];  // 32 KB (broadcast lookup of selected point)
    __shared__ float rv[4];
    __shared__ int ri[4];
    __shared__ int s_last;
    const float* pp = pcd + (size_t)b * NN * 3;
    float px[8], py[8], pz[8], dist[8];
#pragma unroll
    for (int k = 0; k < 8; k++) {
        int i = tid + (k << 8);
        float x = pp[i * 3 + 0], y = pp[i * 3 + 1], z = pp[i * 3 + 2];
        px[k] = x; py[k] = y; pz[k] = z; dist[k] = 1e10f;
        sP[i] = make_float4(x, y, z, 0.0f);
    }
    if (tid == 0) { s_last = 0; fidx[b * NPOINT + 0] = 0; }
    __syncthreads();
    for (int step = 1; step < NPOINT; ++step) {
        int last = s_last;
        float4 lp = sP[last];
        float bv = -1.0f;
        int bi = 0;
#pragma unroll
        for (int k = 0; k < 8; k++) {
            float dx = px[k] - lp.x, dy = py[k] - lp.y, dz = pz[k] - lp.z;
            float d = dx * dx + dy * dy + dz * dz;
            float nd = fminf(dist[k], d);
            dist[k] = nd;
            int idx = tid + (k << 8);
            bool better = nd > bv;  // ascending idx within thread -> first-max kept
            bv = better ? nd : bv;
            bi = better ? idx : bi;
        }
        // wave butterfly argmax (first-index tie-break)
        for (int off = 32; off; off >>= 1) {
            float v2 = __shfl_xor(bv, off, 64);
            int i2 = __shfl_xor(bi, off, 64);
            if (v2 > bv || (v2 == bv && i2 < bi)) { bv = v2; bi = i2; }
        }
        int lane = tid & 63, wid = tid >> 6;
        if (lane == 0) { rv[wid] = bv; ri[wid] = bi; }
        __syncthreads();
        if (tid == 0) {
            float fv = rv[0]; int fi = ri[0];
#pragma unroll
            for (int w = 1; w < 4; w++) {
                if (rv[w] > fv || (rv[w] == fv && ri[w] < fi)) { fv = rv[w]; fi = ri[w]; }
            }
            s_last = fi;
            fidx[b * NPOINT + step] = fi;
        }
        __syncthreads();
    }
}

// ---------------- ball query: 1 wave per (batch, center) ----------------
__global__ __launch_bounds__(64) void k_ball(const float* __restrict__ pcd,
                                             const int* __restrict__ fidx,
                                             int* __restrict__ gidx,
                                             int nsample, float r2) {
    int c = blockIdx.x;
    int b = blockIdx.y;
    int lane = threadIdx.x;
    const float* pp = pcd + (size_t)b * NN * 3;
    int ci = fidx[b * NPOINT + c];
    float cx = pp[ci * 3 + 0], cy = pp[ci * 3 + 1], cz = pp[ci * 3 + 2];
    float sc = cx * cx + cy * cy + cz * cz;
    int* out = gidx + ((size_t)b * NPOINT + c) * nsample;
    int cnt = 0;
    int first = 0;
    for (int j0 = 0; j0 < NN && cnt < nsample; j0 += 64) {
        int j = j0 + lane;
        float x = pp[j * 3 + 0], y = pp[j * 3 + 1], z = pp[j * 3 + 2];
        float sj = x * x + y * y + z * z;
        float d2 = fmaxf(sc + sj - 2.0f * (cx * x + cy * y + cz * z), 0.0f);
        bool pred = d2 < r2;
        unsigned long long mask = __ballot(pred);
        if (cnt == 0 && mask != 0ull) first = j0 + (int)__builtin_ctzll(mask);
        if (pred) {
            int pos = cnt + (int)__popcll(mask & ((1ull << lane) - 1ull));
            if (pos < nsample) out[pos] = j;
        }
        cnt += (int)__popcll(mask);
    }
    if (cnt < nsample) {
        for (int s = cnt + lane; s < nsample; s += 64) out[s] = first;
    }
}

// ---------------- kNN-2 over grouped set (branchless) ----------------
__global__ __launch_bounds__(256) void k_uknn(const float* __restrict__ pcd,
                                              const int* __restrict__ gidx,
                                              int nsample, int M,
                                              double* __restrict__ slot) {
    int b = blockIdx.y;
    __shared__ float4 sP[2448];  // max M, ~39 KB
    __shared__ double sacc[4];
    const float* pp = pcd + (size_t)b * NN * 3;
    const int* gb = gidx + (size_t)b * NPOINT * nsample;
    for (int g = threadIdx.x; g < M; g += 256) {
        int id = gb[g];
        float x = pp[id * 3 + 0], y = pp[id * 3 + 1], z = pp[id * 3 + 2];
        sP[g] = make_float4(x, y, z, 0.0f);
    }
    __syncthreads();
    int i = blockIdx.x * 256 + threadIdx.x;
    float val = 0.0f;
    if (i < M) {
        float4 q = sP[i];
        float m1 = 1e30f, m2 = 1e30f;
#pragma unroll 8
        for (int j = 0; j < M; j++) {
            float4 p = sP[j];
            float dx = q.x - p.x, dy = q.y - p.y, dz = q.z - p.z;
            // direct formula: exact 0 for bit-identical duplicates (padding!)
            float d2 = dx * dx + dy * dy + dz * dz;
            float lo = fminf(m1, d2);
            float hi = fmaxf(m1, d2);
            m1 = lo;
            m2 = fminf(m2, hi);
        }
        val = sqrtf(m2) + 1e-8f;
    }
    block_sum_atomic<4>((double)val, sacc, slot + b);
}

// ---------------- finalize ----------------
__global__ void k_final(const double* __restrict__ acc,
                        const float* __restrict__ radius,
                        float* __restrict__ out) {
    double cd = (0.8 * acc[0] + 0.2 * acc[1]) / ((double)BB * NN) / (double)radius[0];
    double rep = acc[2] / ((double)BB * NN * 4.0);
    const double ps[5] = {0.004, 0.006, 0.008, 0.01, 0.012};
    const int nss[5] = {8, 12, 16, 20, 24};
    double uni = 0.0;
    for (int pi = 0; pi < 5; pi++) {
        double p = ps[pi];
        int M = NPOINT * nss[pi];
        double disk_area = M_PI * 1.0 / (double)NN;
        double e = sqrt(disk_area);
        double bacc = 0.0;
        for (int b = 0; b < BB; b++) {
            double m = acc[3 + pi * 8 + b] / (double)M;
            double d = m - e;
            bacc += d * d / (e + 1e-8);
        }
        uni += (bacc / (double)BB) * (p * 100.0) * (p * 100.0);
    }
    uni /= 5.0;
    out[0] = (float)(cd + rep + uni);
}

extern "C" void kernel_launch(void* const* d_in, const int* in_sizes, int n_in,
                              void* d_out, int out_size, void* d_ws, size_t ws_size,
                              hipStream_t stream) {
    const float* pred = (const float*)d_in[0];
    const float* gt = (const float*)d_in[1];
    const float* radius = (const float*)d_in[2];
    float* out = (float*)d_out;

    double* acc = (double*)d_ws;             // 48 doubles: 0=for 1=bac 2=rep 3..42=uni[5][8]
    int* fidx = (int*)(acc + 48);            // 8*102
    int* gidx = (int*)(fidx + BB * NPOINT);  // up to 8*102*24 (reused across pi)

    hipLaunchKernelGGL(k_init, dim3(1), dim3(64), 0, stream, acc);
    hipLaunchKernelGGL(k_cd2, dim3(NN / 128, BB, 2), dim3(128), 0, stream, pred, gt, acc);
    hipLaunchKernelGGL(k_rep, dim3(NN / 128, BB), dim3(128), 0, stream, pred, acc + 2);
    hipLaunchKernelGGL(k_fps, dim3(BB), dim3(256), 0, stream, pred, fidx);

    const double ps[5] = {0.004, 0.006, 0.008, 0.01, 0.012};
    const int nss[5] = {8, 12, 16, 20, 24};
    for (int pi = 0; pi < 5; pi++) {
        int ns = nss[pi];
        int M = NPOINT * ns;
        float r2 = (float)(sqrt(ps[pi]) * sqrt(ps[pi]));
        hipLaunchKernelGGL(k_ball, dim3(NPOINT, BB), dim3(64), 0, stream,
                           pred, fidx, gidx, ns, r2);
        int nblk = (M + 255) / 256;
        hipLaunchKernelGGL(k_uknn, dim3(nblk, BB), dim3(256), 0, stream,
                           pred, gidx, ns, M, acc + 3 + pi * 8);
    }
    hipLaunchKernelGGL(k_final, dim3(1), dim3(1), 0, stream, acc, radius, out);
}

// Round 3
// 231.189 us; speedup vs baseline: 6.4189x; 2.4832x over previous
//
#include <hip/hip_runtime.h>
#include <math.h>

#define BB 8
#define NN 2048
#define NPOINT 102
#define H_REP 0.0005f

__device__ const int    c_ns[5]   = {8, 12, 16, 20, 24};
__device__ const double c_p[5]    = {0.004, 0.006, 0.008, 0.01, 0.012};
__device__ const int    c_goff[5] = {0, 6528, 16320, 29376, 45696};  // ints; 816*ns prefix

// branchless sorted-5 insert (keeps t0<=t1<=t2<=t3<=t4)
__device__ inline void ins5(float c, float& t0, float& t1, float& t2, float& t3, float& t4) {
    float lo;
    lo = fminf(t0, c); c = fmaxf(t0, c); t0 = lo;
    lo = fminf(t1, c); c = fmaxf(t1, c); t1 = lo;
    lo = fminf(t2, c); c = fmaxf(t2, c); t2 = lo;
    lo = fminf(t3, c); c = fmaxf(t3, c); t3 = lo;
    t4 = fminf(t4, c);
}

// ---------------- chamfer: 4 waves x 512-pt j-chunks, 64 rows/block ----------------
__global__ __launch_bounds__(256) void k_cd(const float* __restrict__ pred,
                                            const float* __restrict__ gt,
                                            double* __restrict__ acc) {
    int z = blockIdx.z;
    int b = blockIdx.y;
    const float* A = z ? pred : gt;
    const float* Bp = z ? gt : pred;
    __shared__ float4 sB[NN];      // 32 KB
    __shared__ float pm[4][64];
    const float* bb = Bp + (size_t)b * NN * 3;
    for (int j = threadIdx.x; j < NN; j += 256) {
        sB[j] = make_float4(bb[j * 3 + 0], bb[j * 3 + 1], bb[j * 3 + 2], 0.0f);
    }
    int lane = threadIdx.x & 63, wid = threadIdx.x >> 6;
    int row = blockIdx.x * 64 + lane;
    const float* aa = A + ((size_t)b * NN + row) * 3;
    float ax = aa[0], ay = aa[1], az = aa[2];
    __syncthreads();
    float mn = 1e30f;
    int j0 = wid * 512;
#pragma unroll 8
    for (int jj = 0; jj < 512; jj++) {
        float4 p = sB[j0 + jj];
        float dx = ax - p.x, dy = ay - p.y, dz = az - p.z;
        mn = fminf(mn, dx * dx + dy * dy + dz * dz);
    }
    pm[wid][lane] = mn;
    __syncthreads();
    double v = 0.0;
    if (threadIdx.x < 64) {
        v = (double)fminf(fminf(pm[0][lane], pm[1][lane]), fminf(pm[2][lane], pm[3][lane]));
    }
    for (int off = 32; off; off >>= 1) v += __shfl_down(v, off, 64);
    if (threadIdx.x == 0) atomicAdd(acc + z, v);
}

// ---------------- repulsion: 8 waves x 256-pt chunks, 64 rows/block ----------------
__global__ __launch_bounds__(512) void k_rep(const float* __restrict__ pcd,
                                             double* __restrict__ slot) {
    int b = blockIdx.y;
    __shared__ float4 sP[NN];        // 32 KB
    __shared__ float pm[8][64][5];   // 10 KB
    const float* pp = pcd + (size_t)b * NN * 3;
    for (int j = threadIdx.x; j < NN; j += 512) {
        sP[j] = make_float4(pp[j * 3 + 0], pp[j * 3 + 1], pp[j * 3 + 2], 0.0f);
    }
    int lane = threadIdx.x & 63, wid = threadIdx.x >> 6;
    int row = blockIdx.x * 64 + lane;
    __syncthreads();
    float4 q = sP[row];
    float t0 = 1e30f, t1 = 1e30f, t2 = 1e30f, t3 = 1e30f, t4 = 1e30f;
    int j0 = wid * 256;
#pragma unroll 8
    for (int jj = 0; jj < 256; jj++) {
        float4 p = sP[j0 + jj];
        float dx = q.x - p.x, dy = q.y - p.y, dz = q.z - p.z;
        ins5(dx * dx + dy * dy + dz * dz, t0, t1, t2, t3, t4);
    }
    pm[wid][lane][0] = t0; pm[wid][lane][1] = t1; pm[wid][lane][2] = t2;
    pm[wid][lane][3] = t3; pm[wid][lane][4] = t4;
    __syncthreads();
    double v = 0.0;
    if (threadIdx.x < 64) {
        t0 = pm[0][lane][0]; t1 = pm[0][lane][1]; t2 = pm[0][lane][2];
        t3 = pm[0][lane][3]; t4 = pm[0][lane][4];
#pragma unroll
        for (int w = 1; w < 8; w++) {
#pragma unroll
            for (int k = 0; k < 5; k++) ins5(pm[w][lane][k], t0, t1, t2, t3, t4);
        }
        float s = fmaxf(H_REP - t1, 0.f) + fmaxf(H_REP - t2, 0.f) +
                  fmaxf(H_REP - t3, 0.f) + fmaxf(H_REP - t4, 0.f);
        v = (double)s;
    }
    for (int off = 32; off; off >>= 1) v += __shfl_down(v, off, 64);
    if (threadIdx.x == 0) atomicAdd(slot, v);
}

// ---------------- FPS: 1 barrier/step, double-buffered argmax slots ----------------
__global__ __launch_bounds__(256) void k_fps(const float* __restrict__ pcd,
                                             int* __restrict__ fidx) {
    int b = blockIdx.x;
    int tid = threadIdx.x;
    __shared__ float4 sP[NN];  // 32 KB
    __shared__ float rv[2][4];
    __shared__ int ri[2][4];
    const float* pp = pcd + (size_t)b * NN * 3;
    float px[8], py[8], pz[8], dist[8];
#pragma unroll
    for (int k = 0; k < 8; k++) {
        int i = tid + (k << 8);
        float x = pp[i * 3 + 0], y = pp[i * 3 + 1], z = pp[i * 3 + 2];
        px[k] = x; py[k] = y; pz[k] = z; dist[k] = 1e10f;
        sP[i] = make_float4(x, y, z, 0.0f);
    }
    if (tid == 0) fidx[b * NPOINT + 0] = 0;
    int last = 0;
    __syncthreads();
    for (int step = 1; step < NPOINT; ++step) {
        float4 lp = sP[last];
        float bv = -1.0f;
        int bi = 0;
#pragma unroll
        for (int k = 0; k < 8; k++) {
            float dx = px[k] - lp.x, dy = py[k] - lp.y, dz = pz[k] - lp.z;
            float nd = fminf(dist[k], dx * dx + dy * dy + dz * dz);
            dist[k] = nd;
            bool better = nd > bv;  // ascending idx in thread -> first-max kept
            bv = better ? nd : bv;
            bi = better ? (tid + (k << 8)) : bi;
        }
        for (int off = 32; off; off >>= 1) {
            float v2 = __shfl_xor(bv, off, 64);
            int i2 = __shfl_xor(bi, off, 64);
            if (v2 > bv || (v2 == bv && i2 < bi)) { bv = v2; bi = i2; }
        }
        int pb = step & 1;
        if ((tid & 63) == 0) { rv[pb][tid >> 6] = bv; ri[pb][tid >> 6] = bi; }
        __syncthreads();
        float fv = rv[pb][0];
        int fi = ri[pb][0];
#pragma unroll
        for (int w = 1; w < 4; w++) {
            float wv = rv[pb][w]; int wi = ri[pb][w];
            if (wv > fv || (wv == fv && wi < fi)) { fv = wv; fi = wi; }
        }
        if (tid == 0) fidx[b * NPOINT + step] = fi;
        last = fi;
    }
}

// ---------------- ball query, all 5 radii fused (z = pi) ----------------
__global__ __launch_bounds__(64) void k_ball(const float* __restrict__ pcd,
                                             const int* __restrict__ fidx,
                                             int* __restrict__ gidx) {
    int c = blockIdx.x;
    int b = blockIdx.y;
    int pi = blockIdx.z;
    int ns = c_ns[pi];
    double rd = sqrt(c_p[pi]);
    float r2 = (float)(rd * rd);
    int lane = threadIdx.x;
    const float* pp = pcd + (size_t)b * NN * 3;
    int ci = fidx[b * NPOINT + c];
    float cx = pp[ci * 3 + 0], cy = pp[ci * 3 + 1], cz = pp[ci * 3 + 2];
    float sc = cx * cx + cy * cy + cz * cz;
    int* out = gidx + c_goff[pi] + ((size_t)b * NPOINT + c) * ns;
    int cnt = 0;
    int first = 0;
    for (int j0 = 0; j0 < NN && cnt < ns; j0 += 64) {
        int j = j0 + lane;
        float x = pp[j * 3 + 0], y = pp[j * 3 + 1], z = pp[j * 3 + 2];
        float sj = x * x + y * y + z * z;
        float d2 = fmaxf(sc + sj - 2.0f * (cx * x + cy * y + cz * z), 0.0f);
        bool pred = d2 < r2;
        unsigned long long mask = __ballot(pred);
        if (cnt == 0 && mask != 0ull) first = j0 + (int)__builtin_ctzll(mask);
        if (pred) {
            int pos = cnt + (int)__popcll(mask & ((1ull << lane) - 1ull));
            if (pos < ns) out[pos] = j;
        }
        cnt += (int)__popcll(mask);
    }
    if (cnt < ns) {
        for (int s = cnt + lane; s < ns; s += 64) out[s] = first;
    }
}

// ---------------- kNN-2, all 5 fused: 4 waves x M/4 chunks, 64 rows/block ----------------
__global__ __launch_bounds__(256) void k_uknn(const float* __restrict__ pcd,
                                              const int* __restrict__ gidx,
                                              double* __restrict__ acc) {
    int pi = blockIdx.z;
    int b = blockIdx.y;
    int ns = c_ns[pi];
    int M = NPOINT * ns;  // 816..2448, divisible by 4
    if (blockIdx.x * 64 >= M) return;
    __shared__ float4 sP[2448];      // ~39 KB
    __shared__ float pm1[4][64], pm2[4][64];
    const float* pp = pcd + (size_t)b * NN * 3;
    const int* gb = gidx + c_goff[pi] + (size_t)b * NPOINT * ns;
    for (int g = threadIdx.x; g < M; g += 256) {
        int id = gb[g];
        sP[g] = make_float4(pp[id * 3 + 0], pp[id * 3 + 1], pp[id * 3 + 2], 0.0f);
    }
    int lane = threadIdx.x & 63, wid = threadIdx.x >> 6;
    int row = blockIdx.x * 64 + lane;
    __syncthreads();
    float4 q = (row < M) ? sP[row] : make_float4(0.f, 0.f, 0.f, 0.f);
    float m1 = 1e30f, m2 = 1e30f;
    int Mq = M >> 2;
    int j0 = wid * Mq;
#pragma unroll 8
    for (int jj = 0; jj < Mq; jj++) {
        float4 p = sP[j0 + jj];
        float dx = q.x - p.x, dy = q.y - p.y, dz = q.z - p.z;
        // direct formula: exact 0 for bit-identical duplicates (padding!)
        float d2 = dx * dx + dy * dy + dz * dz;
        float lo = fminf(m1, d2);
        float hi = fmaxf(m1, d2);
        m1 = lo;
        m2 = fminf(m2, hi);
    }
    pm1[wid][lane] = m1;
    pm2[wid][lane] = m2;
    __syncthreads();
    double v = 0.0;
    if (threadIdx.x < 64 && row < M) {
        float a1 = pm1[0][lane], a2 = pm2[0][lane];
#pragma unroll
        for (int w = 1; w < 4; w++) {
            float b1 = pm1[w][lane], b2 = pm2[w][lane];
            float n1 = fminf(a1, b1);
            float n2 = fminf(fmaxf(a1, b1), fminf(a2, b2));
            a1 = n1; a2 = n2;
        }
        v = (double)(sqrtf(a2) + 1e-8f);
    }
    for (int off = 32; off; off >>= 1) v += __shfl_down(v, off, 64);
    if (threadIdx.x == 0) atomicAdd(acc + 3 + pi * 8 + b, v);
}

// ---------------- finalize ----------------
__global__ void k_final(const double* __restrict__ acc,
                        const float* __restrict__ radius,
                        float* __restrict__ out) {
    double cd = (0.8 * acc[0] + 0.2 * acc[1]) / ((double)BB * NN) / (double)radius[0];
    double rep = acc[2] / ((double)BB * NN * 4.0);
    double uni = 0.0;
    for (int pi = 0; pi < 5; pi++) {
        double p = c_p[pi];
        int M = NPOINT * c_ns[pi];
        double disk_area = M_PI * 1.0 / (double)NN;
        double e = sqrt(disk_area);
        double bacc = 0.0;
        for (int b = 0; b < BB; b++) {
            double m = acc[3 + pi * 8 + b] / (double)M;
            double d = m - e;
            bacc += d * d / (e + 1e-8);
        }
        uni += (bacc / (double)BB) * (p * 100.0) * (p * 100.0);
    }
    uni /= 5.0;
    out[0] = (float)(cd + rep + uni);
}

extern "C" void kernel_launch(void* const* d_in, const int* in_sizes, int n_in,
                              void* d_out, int out_size, void* d_ws, size_t ws_size,
                              hipStream_t stream) {
    const float* pred = (const float*)d_in[0];
    const float* gt = (const float*)d_in[1];
    const float* radius = (const float*)d_in[2];
    float* out = (float*)d_out;

    double* acc = (double*)d_ws;             // 48 doubles: 0=for 1=bac 2=rep 3..42=uni[5][8]
    int* fidx = (int*)(acc + 48);            // 8*102 ints
    int* gidx = (int*)(fidx + BB * NPOINT);  // 65280 ints (all 5 pi regions)

    hipMemsetAsync(acc, 0, 48 * sizeof(double), stream);
    hipLaunchKernelGGL(k_cd, dim3(NN / 64, BB, 2), dim3(256), 0, stream, pred, gt, acc);
    hipLaunchKernelGGL(k_rep, dim3(NN / 64, BB), dim3(512), 0, stream, pred, acc + 2);
    hipLaunchKernelGGL(k_fps, dim3(BB), dim3(256), 0, stream, pred, fidx);
    hipLaunchKernelGGL(k_ball, dim3(NPOINT, BB, 5), dim3(64), 0, stream, pred, fidx, gidx);
    hipLaunchKernelGGL(k_uknn, dim3(39, BB, 5), dim3(256), 0, stream, pred, gidx, acc);
    hipLaunchKernelGGL(k_final, dim3(1), dim3(1), 0, stream, acc, radius, out);
}

// Round 4
// 222.662 us; speedup vs baseline: 6.6647x; 1.0383x over previous
//
#include <hip/hip_runtime.h>
#include <math.h>

#define BB 8
#define NN 2048
#define NPOINT 102
#define H_REP 0.0005f

__device__ const int    c_ns[5]   = {8, 12, 16, 20, 24};
__device__ const double c_p[5]    = {0.004, 0.006, 0.008, 0.01, 0.012};
__device__ const int    c_goff[5] = {0, 6528, 16320, 29376, 45696};  // ints; 816*ns prefix

// branchless sorted-5 insert (keeps t0<=t1<=t2<=t3<=t4)
__device__ inline void ins5(float c, float& t0, float& t1, float& t2, float& t3, float& t4) {
    float lo;
    lo = fminf(t0, c); c = fmaxf(t0, c); t0 = lo;
    lo = fminf(t1, c); c = fmaxf(t1, c); t1 = lo;
    lo = fminf(t2, c); c = fmaxf(t2, c); t2 = lo;
    lo = fminf(t3, c); c = fmaxf(t3, c); t3 = lo;
    t4 = fminf(t4, c);
}

// argmax pair combine: max value, tie -> smaller index (matches jnp.argmax)
__device__ inline void pcomb(float v2, int i2, float& v, int& i) {
    bool take = (v2 > v) || (v2 == v && i2 < i);
    v = take ? v2 : v;
    i = take ? i2 : i;
}

union SMem {
    struct { float4 sB[NN]; float pm[4][64]; } cd;          // 32K + 1K
    struct { float4 sP[NN]; float pm[4][64][5]; } rep;      // 32K + 5K
    struct { float4 sP[NN]; float2 pr[2][16]; } fps;        // 32K + 256B
};

// ---------------- mega kernel: blocks [0,8)=fps  [8,264)=rep  [264,776)=cd ----------------
__global__ __launch_bounds__(256, 4) void k_mega(const float* __restrict__ pred,
                                                 const float* __restrict__ gt,
                                                 int* __restrict__ fidx,
                                                 double* __restrict__ acc) {
    __shared__ SMem sm;
    int bid = blockIdx.x;
    int tid = threadIdx.x;
    int lane = tid & 63, wid = tid >> 6;

    if (bid < 8) {
        // ================= FPS (1 block per batch, 8 pts/thread) =================
        int b = bid;
        const float* pp = pred + (size_t)b * NN * 3;
        float px[8], py[8], pz[8], dist[8];
#pragma unroll
        for (int k = 0; k < 8; k++) {
            int i = tid + (k << 8);
            float x = pp[i * 3 + 0], y = pp[i * 3 + 1], z = pp[i * 3 + 2];
            px[k] = x; py[k] = y; pz[k] = z; dist[k] = 1e10f;
            sm.fps.sP[i] = make_float4(x, y, z, 0.0f);
        }
        if (tid == 0) fidx[b * NPOINT + 0] = 0;
        int last = 0;
        __syncthreads();
        for (int step = 1; step < NPOINT; ++step) {
            float4 lp = sm.fps.sP[last];
            float bv = -1.0f;
            int bi = 0;
#pragma unroll
            for (int k = 0; k < 8; k++) {
                float dx = px[k] - lp.x, dy = py[k] - lp.y, dz = pz[k] - lp.z;
                float nd = fminf(dist[k], dx * dx + dy * dy + dz * dz);
                dist[k] = nd;
                bool better = nd > bv;  // ascending idx in thread -> first-max kept
                bv = better ? nd : bv;
                bi = better ? (tid + (k << 8)) : bi;
            }
            // row (16-lane) argmax reduction via DPP row_ror — VALU latency, no DS ops
            {
                float v2; int i2;
#define RORC(CTRL)                                                                          \
                v2 = __int_as_float(__builtin_amdgcn_update_dpp(                            \
                        __float_as_int(bv), __float_as_int(bv), CTRL, 0xF, 0xF, false));    \
                i2 = __builtin_amdgcn_update_dpp(bi, bi, CTRL, 0xF, 0xF, false);            \
                pcomb(v2, i2, bv, bi);
                RORC(0x121)  // row_ror:1
                RORC(0x122)  // row_ror:2
                RORC(0x124)  // row_ror:4
                RORC(0x128)  // row_ror:8
#undef RORC
            }
            int pb = step & 1;
            if ((tid & 15) == 0) sm.fps.pr[pb][tid >> 4] = make_float2(bv, __int_as_float(bi));
            __syncthreads();
            float fv = -2.0f;
            int fi = 0;
#pragma unroll
            for (int r = 0; r < 16; r++) {
                float2 pr = sm.fps.pr[pb][r];
                pcomb(pr.x, __float_as_int(pr.y), fv, fi);
            }
            if (tid == 0) fidx[b * NPOINT + step] = fi;
            last = fi;  // uniform across block
        }
    } else if (bid < 264) {
        // ================= repulsion: 4 waves x 512-pt chunks, 64 rows =================
        int r = bid - 8;
        int b = r >> 5;
        int xb = r & 31;
        const float* pp = pred + (size_t)b * NN * 3;
        for (int j = tid; j < NN; j += 256) {
            sm.rep.sP[j] = make_float4(pp[j * 3 + 0], pp[j * 3 + 1], pp[j * 3 + 2], 0.0f);
        }
        int row = xb * 64 + lane;
        __syncthreads();
        float4 q = sm.rep.sP[row];
        float t0 = 1e30f, t1 = 1e30f, t2 = 1e30f, t3 = 1e30f, t4 = 1e30f;
        int j0 = wid * 512;
#pragma unroll 8
        for (int jj = 0; jj < 512; jj++) {
            float4 p = sm.rep.sP[j0 + jj];
            float dx = q.x - p.x, dy = q.y - p.y, dz = q.z - p.z;
            ins5(dx * dx + dy * dy + dz * dz, t0, t1, t2, t3, t4);
        }
        sm.rep.pm[wid][lane][0] = t0; sm.rep.pm[wid][lane][1] = t1;
        sm.rep.pm[wid][lane][2] = t2; sm.rep.pm[wid][lane][3] = t3;
        sm.rep.pm[wid][lane][4] = t4;
        __syncthreads();
        double v = 0.0;
        if (tid < 64) {
            t0 = sm.rep.pm[0][lane][0]; t1 = sm.rep.pm[0][lane][1]; t2 = sm.rep.pm[0][lane][2];
            t3 = sm.rep.pm[0][lane][3]; t4 = sm.rep.pm[0][lane][4];
#pragma unroll
            for (int w = 1; w < 4; w++) {
#pragma unroll
                for (int k = 0; k < 5; k++) ins5(sm.rep.pm[w][lane][k], t0, t1, t2, t3, t4);
            }
            float s = fmaxf(H_REP - t1, 0.f) + fmaxf(H_REP - t2, 0.f) +
                      fmaxf(H_REP - t3, 0.f) + fmaxf(H_REP - t4, 0.f);
            v = (double)s;
        }
        for (int off = 32; off; off >>= 1) v += __shfl_down(v, off, 64);
        if (tid == 0) atomicAdd(acc + 2, v);
    } else {
        // ================= chamfer: 4 waves x 512-pt chunks, 64 rows =================
        int r = bid - 264;
        int z = r >> 8;
        int b = (r >> 5) & 7;
        int xb = r & 31;
        const float* A = z ? pred : gt;
        const float* Bp = z ? gt : pred;
        const float* bb = Bp + (size_t)b * NN * 3;
        for (int j = tid; j < NN; j += 256) {
            sm.cd.sB[j] = make_float4(bb[j * 3 + 0], bb[j * 3 + 1], bb[j * 3 + 2], 0.0f);
        }
        int row = xb * 64 + lane;
        const float* aa = A + ((size_t)b * NN + row) * 3;
        float ax = aa[0], ay = aa[1], az = aa[2];
        __syncthreads();
        float mn = 1e30f;
        int j0 = wid * 512;
#pragma unroll 8
        for (int jj = 0; jj < 512; jj++) {
            float4 p = sm.cd.sB[j0 + jj];
            float dx = ax - p.x, dy = ay - p.y, dz = az - p.z;
            mn = fminf(mn, dx * dx + dy * dy + dz * dz);
        }
        sm.cd.pm[wid][lane] = mn;
        __syncthreads();
        double v = 0.0;
        if (tid < 64) {
            v = (double)fminf(fminf(sm.cd.pm[0][lane], sm.cd.pm[1][lane]),
                              fminf(sm.cd.pm[2][lane], sm.cd.pm[3][lane]));
        }
        for (int off = 32; off; off >>= 1) v += __shfl_down(v, off, 64);
        if (tid == 0) atomicAdd(acc + z, v);
    }
}

// ---------------- ball query, all 5 radii fused (z = pi) ----------------
__global__ __launch_bounds__(64) void k_ball(const float* __restrict__ pcd,
                                             const int* __restrict__ fidx,
                                             int* __restrict__ gidx) {
    int c = blockIdx.x;
    int b = blockIdx.y;
    int pi = blockIdx.z;
    int ns = c_ns[pi];
    double rd = sqrt(c_p[pi]);
    float r2 = (float)(rd * rd);
    int lane = threadIdx.x;
    const float* pp = pcd + (size_t)b * NN * 3;
    int ci = fidx[b * NPOINT + c];
    float cx = pp[ci * 3 + 0], cy = pp[ci * 3 + 1], cz = pp[ci * 3 + 2];
    float sc = cx * cx + cy * cy + cz * cz;
    int* out = gidx + c_goff[pi] + ((size_t)b * NPOINT + c) * ns;
    int cnt = 0;
    int first = 0;
    for (int j0 = 0; j0 < NN && cnt < ns; j0 += 64) {
        int j = j0 + lane;
        float x = pp[j * 3 + 0], y = pp[j * 3 + 1], z = pp[j * 3 + 2];
        float sj = x * x + y * y + z * z;
        float d2 = fmaxf(sc + sj - 2.0f * (cx * x + cy * y + cz * z), 0.0f);
        bool pred = d2 < r2;
        unsigned long long mask = __ballot(pred);
        if (cnt == 0 && mask != 0ull) first = j0 + (int)__builtin_ctzll(mask);
        if (pred) {
            int pos = cnt + (int)__popcll(mask & ((1ull << lane) - 1ull));
            if (pos < ns) out[pos] = j;
        }
        cnt += (int)__popcll(mask);
    }
    if (cnt < ns) {
        for (int s = cnt + lane; s < ns; s += 64) out[s] = first;
    }
}

// ---------------- kNN-2, all 5 fused: 4 waves x M/4 chunks, 64 rows/block ----------------
__global__ __launch_bounds__(256) void k_uknn(const float* __restrict__ pcd,
                                              const int* __restrict__ gidx,
                                              double* __restrict__ acc) {
    int pi = blockIdx.z;
    int b = blockIdx.y;
    int ns = c_ns[pi];
    int M = NPOINT * ns;  // 816..2448, divisible by 4
    if (blockIdx.x * 64 >= M) return;
    __shared__ float4 sP[2448];  // ~39 KB
    __shared__ float pm1[4][64], pm2[4][64];
    const float* pp = pcd + (size_t)b * NN * 3;
    const int* gb = gidx + c_goff[pi] + (size_t)b * NPOINT * ns;
    for (int g = threadIdx.x; g < M; g += 256) {
        int id = gb[g];
        sP[g] = make_float4(pp[id * 3 + 0], pp[id * 3 + 1], pp[id * 3 + 2], 0.0f);
    }
    int lane = threadIdx.x & 63, wid = threadIdx.x >> 6;
    int row = blockIdx.x * 64 + lane;
    __syncthreads();
    float4 q = (row < M) ? sP[row] : make_float4(0.f, 0.f, 0.f, 0.f);
    float m1 = 1e30f, m2 = 1e30f;
    int Mq = M >> 2;
    int j0 = wid * Mq;
#pragma unroll 8
    for (int jj = 0; jj < Mq; jj++) {
        float4 p = sP[j0 + jj];
        float dx = q.x - p.x, dy = q.y - p.y, dz = q.z - p.z;
        // direct formula: exact 0 for bit-identical duplicates (padding!)
        float d2 = dx * dx + dy * dy + dz * dz;
        float lo = fminf(m1, d2);
        float hi = fmaxf(m1, d2);
        m1 = lo;
        m2 = fminf(m2, hi);
    }
    pm1[wid][lane] = m1;
    pm2[wid][lane] = m2;
    __syncthreads();
    double v = 0.0;
    if (threadIdx.x < 64 && row < M) {
        float a1 = pm1[0][lane], a2 = pm2[0][lane];
#pragma unroll
        for (int w = 1; w < 4; w++) {
            float b1 = pm1[w][lane], b2 = pm2[w][lane];
            float n1 = fminf(a1, b1);
            float n2 = fminf(fmaxf(a1, b1), fminf(a2, b2));
            a1 = n1; a2 = n2;
        }
        v = (double)(sqrtf(a2) + 1e-8f);
    }
    for (int off = 32; off; off >>= 1) v += __shfl_down(v, off, 64);
    if (threadIdx.x == 0) atomicAdd(acc + 3 + pi * 8 + b, v);
}

// ---------------- finalize ----------------
__global__ void k_final(const double* __restrict__ acc,
                        const float* __restrict__ radius,
                        float* __restrict__ out) {
    double cd = (0.8 * acc[0] + 0.2 * acc[1]) / ((double)BB * NN) / (double)radius[0];
    double rep = acc[2] / ((double)BB * NN * 4.0);
    double uni = 0.0;
    for (int pi = 0; pi < 5; pi++) {
        double p = c_p[pi];
        int M = NPOINT * c_ns[pi];
        double disk_area = M_PI * 1.0 / (double)NN;
        double e = sqrt(disk_area);
        double bacc = 0.0;
        for (int b = 0; b < BB; b++) {
            double m = acc[3 + pi * 8 + b] / (double)M;
            double d = m - e;
            bacc += d * d / (e + 1e-8);
        }
        uni += (bacc / (double)BB) * (p * 100.0) * (p * 100.0);
    }
    uni /= 5.0;
    out[0] = (float)(cd + rep + uni);
}

extern "C" void kernel_launch(void* const* d_in, const int* in_sizes, int n_in,
                              void* d_out, int out_size, void* d_ws, size_t ws_size,
                              hipStream_t stream) {
    const float* pred = (const float*)d_in[0];
    const float* gt = (const float*)d_in[1];
    const float* radius = (const float*)d_in[2];
    float* out = (float*)d_out;

    double* acc = (double*)d_ws;             // 48 doubles: 0=for 1=bac 2=rep 3..42=uni[5][8]
    int* fidx = (int*)(acc + 48);            // 8*102 ints
    int* gidx = (int*)(fidx + BB * NPOINT);  // 65280 ints (all 5 pi regions)

    hipMemsetAsync(acc, 0, 48 * sizeof(double), stream);
    hipLaunchKernelGGL(k_mega, dim3(776), dim3(256), 0, stream, pred, gt, fidx, acc);
    hipLaunchKernelGGL(k_ball, dim3(NPOINT, BB, 5), dim3(64), 0, stream, pred, fidx, gidx);
    hipLaunchKernelGGL(k_uknn, dim3(39, BB, 5), dim3(256), 0, stream, pred, gidx, acc);
    hipLaunchKernelGGL(k_final, dim3(1), dim3(1), 0, stream, acc, radius, out);
}

// Round 5
// 186.373 us; speedup vs baseline: 7.9624x; 1.1947x over previous
//
#include <hip/hip_runtime.h>
#include <math.h>

#define BB 8
#define NN 2048
#define NPOINT 102
#define H_REP 0.0005f

__device__ const int    c_ns[5]   = {8, 12, 16, 20, 24};
__device__ const double c_p[5]    = {0.004, 0.006, 0.008, 0.01, 0.012};
__device__ const int    c_goff[5] = {0, 6528, 16320, 29376, 45696};  // ints; 816*ns prefix

// branchless sorted-5 insert (keeps t0<=t1<=t2<=t3<=t4)
__device__ inline void ins5(float c, float& t0, float& t1, float& t2, float& t3, float& t4) {
    float lo;
    lo = fminf(t0, c); c = fmaxf(t0, c); t0 = lo;
    lo = fminf(t1, c); c = fmaxf(t1, c); t1 = lo;
    lo = fminf(t2, c); c = fmaxf(t2, c); t2 = lo;
    lo = fminf(t3, c); c = fmaxf(t3, c); t3 = lo;
    t4 = fminf(t4, c);
}

// argmax pair combine: max value, tie -> smaller index (matches jnp.argmax)
__device__ inline void pcomb(float v2, int i2, float& v, int& i) {
    bool take = (v2 > v) || (v2 == v && i2 < i);
    v = take ? v2 : v;
    i = take ? i2 : i;
}

union SMem {
    struct { float4 sB[NN]; float pm[4][128]; } cd;        // 32K + 2K
    struct { float4 sP[NN]; float pm[4][64][5]; } rep;     // 32K + 5K
    struct { float4 sP[NN]; } fps;                         // 32K
};

// ---------------- phase1: blocks [0,8)=fps  [8,264)=cd  [264,520)=rep ----------------
__global__ __launch_bounds__(256) void k_phase1(const float* __restrict__ pred,
                                                const float* __restrict__ gt,
                                                int* __restrict__ fidx,
                                                double* __restrict__ acc) {
    __shared__ SMem sm;
    int bid = blockIdx.x;
    int tid = threadIdx.x;
    int lane = tid & 63, wid = tid >> 6;

    if (bid < 8) {
        // ========== FPS: ONE wave, 32 pts/lane in VGPRs, no barriers, DPP argmax ==========
        if (tid >= 64) return;  // only wave 0 (no __syncthreads in this branch)
        __builtin_amdgcn_s_setprio(1);
        int b = bid;
        const float* pp = pred + (size_t)b * NN * 3;
        float px[32], py[32], pz[32], dist[32];
#pragma unroll
        for (int k = 0; k < 32; k++) {
            int i = tid + (k << 6);
            float x = pp[i * 3 + 0], y = pp[i * 3 + 1], z = pp[i * 3 + 2];
            px[k] = x; py[k] = y; pz[k] = z; dist[k] = 1e10f;
            sm.fps.sP[i] = make_float4(x, y, z, 0.0f);
        }
        if (tid == 0) fidx[b * NPOINT + 0] = 0;
        int last = 0;
#pragma unroll 1
        for (int step = 1; step < NPOINT; ++step) {
            float4 lp = sm.fps.sP[last];  // single-wave: waitcnt orders vs our own writes
            float bv = -1.0f;
            int bi = 0;
#pragma unroll
            for (int k = 0; k < 32; k++) {
                float dx = px[k] - lp.x, dy = py[k] - lp.y, dz = pz[k] - lp.z;
                float nd = fminf(dist[k], dx * dx + dy * dy + dz * dz);
                dist[k] = nd;
                bool better = nd > bv;  // ascending idx in lane -> first-max kept
                bv = better ? nd : bv;
                bi = better ? (tid + (k << 6)) : bi;
            }
            // full wave-64 argmax in-register: row_ror 1,2,4,8 then bcast15, bcast31.
            // pcomb is idempotent (max, tie->min idx) so bcast double-combines are safe.
            {
                float v2; int i2;
#define DPPC(CTRL)                                                                          \
                v2 = __int_as_float(__builtin_amdgcn_update_dpp(                            \
                        __float_as_int(bv), __float_as_int(bv), CTRL, 0xF, 0xF, false));    \
                i2 = __builtin_amdgcn_update_dpp(bi, bi, CTRL, 0xF, 0xF, false);            \
                pcomb(v2, i2, bv, bi);
                DPPC(0x121)  // row_ror:1
                DPPC(0x122)  // row_ror:2
                DPPC(0x124)  // row_ror:4
                DPPC(0x128)  // row_ror:8
                DPPC(0x142)  // row_bcast15
                DPPC(0x143)  // row_bcast31
#undef DPPC
            }
            int fi = __shfl(bi, 63, 64);  // lane 63 holds global argmax
            if (tid == 0) fidx[b * NPOINT + step] = fi;
            last = fi;
        }
    } else if (bid < 264) {
        // ========== chamfer: 2 rows/lane (128 rows/block), 4 waves x 512-pt chunks ==========
        int r = bid - 8;
        int z = r >> 7;
        int b = (r >> 4) & 7;
        int xb = r & 15;
        const float* A = z ? pred : gt;
        const float* Bp = z ? gt : pred;
        const float* bb = Bp + (size_t)b * NN * 3;
        for (int j = tid; j < NN; j += 256) {
            sm.cd.sB[j] = make_float4(bb[j * 3 + 0], bb[j * 3 + 1], bb[j * 3 + 2], 0.0f);
        }
        int rowA = xb * 128 + lane;
        int rowB = rowA + 64;
        const float* aA = A + ((size_t)b * NN + rowA) * 3;
        const float* aB = A + ((size_t)b * NN + rowB) * 3;
        float axA = aA[0], ayA = aA[1], azA = aA[2];
        float axB = aB[0], ayB = aB[1], azB = aB[2];
        __syncthreads();
        float mnA = 1e30f, mnB = 1e30f;
        int j0 = wid * 512;
#pragma unroll 8
        for (int jj = 0; jj < 512; jj++) {
            float4 p = sm.cd.sB[j0 + jj];
            float dxA = axA - p.x, dyA = ayA - p.y, dzA = azA - p.z;
            mnA = fminf(mnA, dxA * dxA + dyA * dyA + dzA * dzA);
            float dxB = axB - p.x, dyB = ayB - p.y, dzB = azB - p.z;
            mnB = fminf(mnB, dxB * dxB + dyB * dyB + dzB * dzB);
        }
        sm.cd.pm[wid][lane] = mnA;
        sm.cd.pm[wid][64 + lane] = mnB;
        __syncthreads();
        if (tid < 128) {
            double v = (double)fminf(fminf(sm.cd.pm[0][tid], sm.cd.pm[1][tid]),
                                     fminf(sm.cd.pm[2][tid], sm.cd.pm[3][tid]));
            for (int off = 32; off; off >>= 1) v += __shfl_down(v, off, 64);
            if (lane == 0) atomicAdd(acc + z, v);
        }
    } else {
        // ========== repulsion: 4 waves x 512-pt chunks, 64 rows/block ==========
        int r = bid - 264;
        int b = r >> 5;
        int xb = r & 31;
        const float* pp = pred + (size_t)b * NN * 3;
        for (int j = tid; j < NN; j += 256) {
            sm.rep.sP[j] = make_float4(pp[j * 3 + 0], pp[j * 3 + 1], pp[j * 3 + 2], 0.0f);
        }
        int row = xb * 64 + lane;
        __syncthreads();
        float4 q = sm.rep.sP[row];
        float t0 = 1e30f, t1 = 1e30f, t2 = 1e30f, t3 = 1e30f, t4 = 1e30f;
        int j0 = wid * 512;
#pragma unroll 8
        for (int jj = 0; jj < 512; jj++) {
            float4 p = sm.rep.sP[j0 + jj];
            float dx = q.x - p.x, dy = q.y - p.y, dz = q.z - p.z;
            ins5(dx * dx + dy * dy + dz * dz, t0, t1, t2, t3, t4);
        }
        sm.rep.pm[wid][lane][0] = t0; sm.rep.pm[wid][lane][1] = t1;
        sm.rep.pm[wid][lane][2] = t2; sm.rep.pm[wid][lane][3] = t3;
        sm.rep.pm[wid][lane][4] = t4;
        __syncthreads();
        double v = 0.0;
        if (tid < 64) {
            t0 = sm.rep.pm[0][lane][0]; t1 = sm.rep.pm[0][lane][1]; t2 = sm.rep.pm[0][lane][2];
            t3 = sm.rep.pm[0][lane][3]; t4 = sm.rep.pm[0][lane][4];
#pragma unroll
            for (int w = 1; w < 4; w++) {
#pragma unroll
                for (int k = 0; k < 5; k++) ins5(sm.rep.pm[w][lane][k], t0, t1, t2, t3, t4);
            }
            float s = fmaxf(H_REP - t1, 0.f) + fmaxf(H_REP - t2, 0.f) +
                      fmaxf(H_REP - t3, 0.f) + fmaxf(H_REP - t4, 0.f);
            v = (double)s;
            for (int off = 32; off; off >>= 1) v += __shfl_down(v, off, 64);
            if (tid == 0) atomicAdd(acc + 2, v);
        }
    }
}

// ---------------- ball query, all 5 radii fused (z = pi) ----------------
__global__ __launch_bounds__(64) void k_ball(const float* __restrict__ pcd,
                                             const int* __restrict__ fidx,
                                             int* __restrict__ gidx) {
    int c = blockIdx.x;
    int b = blockIdx.y;
    int pi = blockIdx.z;
    int ns = c_ns[pi];
    double rd = sqrt(c_p[pi]);
    float r2 = (float)(rd * rd);
    int lane = threadIdx.x;
    const float* pp = pcd + (size_t)b * NN * 3;
    int ci = fidx[b * NPOINT + c];
    float cx = pp[ci * 3 + 0], cy = pp[ci * 3 + 1], cz = pp[ci * 3 + 2];
    float sc = cx * cx + cy * cy + cz * cz;
    int* out = gidx + c_goff[pi] + ((size_t)b * NPOINT + c) * ns;
    int cnt = 0;
    int first = 0;
    for (int j0 = 0; j0 < NN && cnt < ns; j0 += 64) {
        int j = j0 + lane;
        float x = pp[j * 3 + 0], y = pp[j * 3 + 1], z = pp[j * 3 + 2];
        float sj = x * x + y * y + z * z;
        float d2 = fmaxf(sc + sj - 2.0f * (cx * x + cy * y + cz * z), 0.0f);
        bool pred = d2 < r2;
        unsigned long long mask = __ballot(pred);
        if (cnt == 0 && mask != 0ull) first = j0 + (int)__builtin_ctzll(mask);
        if (pred) {
            int pos = cnt + (int)__popcll(mask & ((1ull << lane) - 1ull));
            if (pos < ns) out[pos] = j;
        }
        cnt += (int)__popcll(mask);
    }
    if (cnt < ns) {
        for (int s = cnt + lane; s < ns; s += 64) out[s] = first;
    }
}

// ---------------- kNN-2, all 5 fused: 2 rows/lane, 4 waves x M/4 chunks ----------------
__global__ __launch_bounds__(256) void k_uknn(const float* __restrict__ pcd,
                                              const int* __restrict__ gidx,
                                              double* __restrict__ acc) {
    int pi = blockIdx.z;
    int b = blockIdx.y;
    int ns = c_ns[pi];
    int M = NPOINT * ns;  // 816..2448, divisible by 4
    if (blockIdx.x * 128 >= M) return;
    __shared__ float4 sP[2448];  // ~39 KB
    __shared__ float pm1[4][128], pm2[4][128];
    const float* pp = pcd + (size_t)b * NN * 3;
    const int* gb = gidx + c_goff[pi] + (size_t)b * NPOINT * ns;
    for (int g = threadIdx.x; g < M; g += 256) {
        int id = gb[g];
        sP[g] = make_float4(pp[id * 3 + 0], pp[id * 3 + 1], pp[id * 3 + 2], 0.0f);
    }
    int lane = threadIdx.x & 63, wid = threadIdx.x >> 6;
    int rowA = blockIdx.x * 128 + lane;
    int rowB = rowA + 64;
    __syncthreads();
    float4 qA = (rowA < M) ? sP[rowA] : make_float4(0.f, 0.f, 0.f, 0.f);
    float4 qB = (rowB < M) ? sP[rowB] : make_float4(0.f, 0.f, 0.f, 0.f);
    float m1A = 1e30f, m2A = 1e30f, m1B = 1e30f, m2B = 1e30f;
    int Mq = M >> 2;
    int j0 = wid * Mq;
#pragma unroll 4
    for (int jj = 0; jj < Mq; jj++) {
        float4 p = sP[j0 + jj];
        // direct formula: exact 0 for bit-identical duplicates (padding!)
        float dxA = qA.x - p.x, dyA = qA.y - p.y, dzA = qA.z - p.z;
        float dA = dxA * dxA + dyA * dyA + dzA * dzA;
        float loA = fminf(m1A, dA), hiA = fmaxf(m1A, dA);
        m1A = loA; m2A = fminf(m2A, hiA);
        float dxB = qB.x - p.x, dyB = qB.y - p.y, dzB = qB.z - p.z;
        float dB = dxB * dxB + dyB * dyB + dzB * dzB;
        float loB = fminf(m1B, dB), hiB = fmaxf(m1B, dB);
        m1B = loB; m2B = fminf(m2B, hiB);
    }
    pm1[wid][lane] = m1A; pm2[wid][lane] = m2A;
    pm1[wid][64 + lane] = m1B; pm2[wid][64 + lane] = m2B;
    __syncthreads();
    if (threadIdx.x < 128) {
        int row = blockIdx.x * 128 + threadIdx.x;
        double v = 0.0;
        if (row < M) {
            float a1 = pm1[0][threadIdx.x], a2 = pm2[0][threadIdx.x];
#pragma unroll
            for (int w = 1; w < 4; w++) {
                float b1 = pm1[w][threadIdx.x], b2 = pm2[w][threadIdx.x];
                float n1 = fminf(a1, b1);
                float n2 = fminf(fmaxf(a1, b1), fminf(a2, b2));
                a1 = n1; a2 = n2;
            }
            v = (double)(sqrtf(a2) + 1e-8f);
        }
        for (int off = 32; off; off >>= 1) v += __shfl_down(v, off, 64);
        if (lane == 0) atomicAdd(acc + 3 + pi * 8 + b, v);
    }
}

// ---------------- finalize ----------------
__global__ void k_final(const double* __restrict__ acc,
                        const float* __restrict__ radius,
                        float* __restrict__ out) {
    double cd = (0.8 * acc[0] + 0.2 * acc[1]) / ((double)BB * NN) / (double)radius[0];
    double rep = acc[2] / ((double)BB * NN * 4.0);
    double uni = 0.0;
    for (int pi = 0; pi < 5; pi++) {
        double p = c_p[pi];
        int M = NPOINT * c_ns[pi];
        double disk_area = M_PI * 1.0 / (double)NN;
        double e = sqrt(disk_area);
        double bacc = 0.0;
        for (int b = 0; b < BB; b++) {
            double m = acc[3 + pi * 8 + b] / (double)M;
            double d = m - e;
            bacc += d * d / (e + 1e-8);
        }
        uni += (bacc / (double)BB) * (p * 100.0) * (p * 100.0);
    }
    uni /= 5.0;
    out[0] = (float)(cd + rep + uni);
}

extern "C" void kernel_launch(void* const* d_in, const int* in_sizes, int n_in,
                              void* d_out, int out_size, void* d_ws, size_t ws_size,
                              hipStream_t stream) {
    const float* pred = (const float*)d_in[0];
    const float* gt = (const float*)d_in[1];
    const float* radius = (const float*)d_in[2];
    float* out = (float*)d_out;

    double* acc = (double*)d_ws;             // 48 doubles: 0=for 1=bac 2=rep 3..42=uni[5][8]
    int* fidx = (int*)(acc + 48);            // 8*102 ints
    int* gidx = (int*)(fidx + BB * NPOINT);  // 65280 ints (all 5 pi regions)

    hipMemsetAsync(acc, 0, 48 * sizeof(double), stream);
    hipLaunchKernelGGL(k_phase1, dim3(520), dim3(256), 0, stream, pred, gt, fidx, acc);
    hipLaunchKernelGGL(k_ball, dim3(NPOINT, BB, 5), dim3(64), 0, stream, pred, fidx, gidx);
    hipLaunchKernelGGL(k_uknn, dim3(20, BB, 5), dim3(256), 0, stream, pred, gidx, acc);
    hipLaunchKernelGGL(k_final, dim3(1), dim3(1), 0, stream, acc, radius, out);
}

// Round 6
// 165.251 us; speedup vs baseline: 8.9801x; 1.1278x over previous
//
#include <hip/hip_runtime.h>
#include <math.h>

#define BB 8
#define NN 2048
#define NPOINT 102
#define H_REP 0.0005f

typedef float v2f __attribute__((ext_vector_type(2)));

__device__ const int    c_ns[5]   = {8, 12, 16, 20, 24};
__device__ const double c_p[5]    = {0.004, 0.006, 0.008, 0.01, 0.012};
__device__ const int    c_goff[5] = {0, 6528, 16320, 29376, 45696};  // ints; 816*ns prefix

// branchless sorted-5 insert (keeps t0<=t1<=t2<=t3<=t4)
__device__ inline void ins5(float c, float& t0, float& t1, float& t2, float& t3, float& t4) {
    float lo;
    lo = fminf(t0, c); c = fmaxf(t0, c); t0 = lo;
    lo = fminf(t1, c); c = fmaxf(t1, c); t1 = lo;
    lo = fminf(t2, c); c = fmaxf(t2, c); t2 = lo;
    lo = fminf(t3, c); c = fmaxf(t3, c); t3 = lo;
    t4 = fminf(t4, c);
}

// argmax pair combine: max value, tie -> smaller index (matches jnp.argmax)
__device__ inline void pcomb(float v2, int i2, float& v, int& i) {
    bool take = (v2 > v) || (v2 == v && i2 < i);
    v = take ? v2 : v;
    i = take ? i2 : i;
}

union SMem {
    struct { float4 sB[NN]; float pm[4][128]; } cd;        // 32K + 2K
    struct { float4 sP[NN]; float pm[4][64][5]; } rep;     // 32K + 5K
    struct { float4 sP[NN]; } fps;                         // 32K
};

// ---------------- phase1: blocks [0,8)=fps  [8,264)=cd  [264,520)=rep ----------------
__global__ __launch_bounds__(256, 2) void k_phase1(const float* __restrict__ pred,
                                                   const float* __restrict__ gt,
                                                   int* __restrict__ fidx,
                                                   double* __restrict__ acc) {
    __shared__ SMem sm;
    int bid = blockIdx.x;
    int tid = threadIdx.x;
    int lane = tid & 63, wid = tid >> 6;

    if (bid < 8) {
        // ========== FPS: ONE wave, 32 pts/lane, packed-f32 dist, tree+DPP argmax ==========
        if (tid >= 64) return;  // only wave 0 (no __syncthreads in this branch)
        __builtin_amdgcn_s_setprio(1);
        int b = bid;
        const float* pp = pred + (size_t)b * NN * 3;
        v2f px[16], py[16], pz[16], dist[16];
#pragma unroll
        for (int kk = 0; kk < 16; kk++) {
            int i0 = tid + ((2 * kk) << 6);
            int i1 = i0 + 64;
            float x0 = pp[i0 * 3 + 0], y0 = pp[i0 * 3 + 1], z0 = pp[i0 * 3 + 2];
            float x1 = pp[i1 * 3 + 0], y1 = pp[i1 * 3 + 1], z1 = pp[i1 * 3 + 2];
            px[kk] = (v2f){x0, x1}; py[kk] = (v2f){y0, y1}; pz[kk] = (v2f){z0, z1};
            dist[kk] = (v2f){1e10f, 1e10f};
            sm.fps.sP[i0] = make_float4(x0, y0, z0, 0.f);
            sm.fps.sP[i1] = make_float4(x1, y1, z1, 0.f);
        }
        if (tid == 0) fidx[b * NPOINT + 0] = 0;
        int last = 0;
#pragma unroll 1
        for (int step = 1; step < NPOINT; ++step) {
            float4 lp = sm.fps.sP[last];  // single-wave: waitcnt orders vs our own writes
            v2f lx = {lp.x, lp.x}, ly = {lp.y, lp.y}, lz = {lp.z, lp.z};
            float tv[32];
            int tk[32];
#pragma unroll
            for (int kk = 0; kk < 16; kk++) {
                v2f dx = px[kk] - lx, dy = py[kk] - ly, dz = pz[kk] - lz;
                v2f d2 = dx * dx + dy * dy + dz * dz;  // v_pk_mul/fma_f32
                float n0 = fminf(dist[kk].x, d2.x);
                float n1 = fminf(dist[kk].y, d2.y);
                dist[kk] = (v2f){n0, n1};
                tv[2 * kk] = n0; tk[2 * kk] = 2 * kk;
                tv[2 * kk + 1] = n1; tk[2 * kk + 1] = 2 * kk + 1;
            }
            // in-lane tree argmax over 32 (ties -> smaller k, = smaller global idx)
#pragma unroll
            for (int s = 1; s < 32; s <<= 1) {
#pragma unroll
                for (int k = 0; k < 32; k += 2 * s) {
                    pcomb(tv[k + s], tk[k + s], tv[k], tk[k]);
                }
            }
            float bv = tv[0];
            int bi = tid + (tk[0] << 6);
            // wave-64 argmax in-register: row_ror 1,2,4,8 then bcast15, bcast31.
            // pcomb is idempotent (max, tie->min idx) so bcast double-combines are safe.
            {
                float v2; int i2;
#define DPPC(CTRL)                                                                          \
                v2 = __int_as_float(__builtin_amdgcn_update_dpp(                            \
                        __float_as_int(bv), __float_as_int(bv), CTRL, 0xF, 0xF, false));    \
                i2 = __builtin_amdgcn_update_dpp(bi, bi, CTRL, 0xF, 0xF, false);            \
                pcomb(v2, i2, bv, bi);
                DPPC(0x121)  // row_ror:1
                DPPC(0x122)  // row_ror:2
                DPPC(0x124)  // row_ror:4
                DPPC(0x128)  // row_ror:8
                DPPC(0x142)  // row_bcast15
                DPPC(0x143)  // row_bcast31
#undef DPPC
            }
            int fi = __builtin_amdgcn_readlane(bi, 63);  // SALU broadcast, no DS op
            if (tid == 0) fidx[b * NPOINT + step] = fi;
            last = fi;
        }
    } else if (bid < 264) {
        // ========== chamfer: 2 rows/lane (128 rows/block), 4 waves x 512-pt chunks ==========
        int r = bid - 8;
        int z = r >> 7;
        int b = (r >> 4) & 7;
        int xb = r & 15;
        const float* A = z ? pred : gt;
        const float* Bp = z ? gt : pred;
        const float* bb = Bp + (size_t)b * NN * 3;
        for (int j = tid; j < NN; j += 256) {
            sm.cd.sB[j] = make_float4(bb[j * 3 + 0], bb[j * 3 + 1], bb[j * 3 + 2], 0.0f);
        }
        int rowA = xb * 128 + lane;
        int rowB = rowA + 64;
        const float* aA = A + ((size_t)b * NN + rowA) * 3;
        const float* aB = A + ((size_t)b * NN + rowB) * 3;
        float axA = aA[0], ayA = aA[1], azA = aA[2];
        float axB = aB[0], ayB = aB[1], azB = aB[2];
        __syncthreads();
        float mnA = 1e30f, mnB = 1e30f;
        int j0 = wid * 512;
#pragma unroll 8
        for (int jj = 0; jj < 512; jj++) {
            float4 p = sm.cd.sB[j0 + jj];
            float dxA = axA - p.x, dyA = ayA - p.y, dzA = azA - p.z;
            mnA = fminf(mnA, dxA * dxA + dyA * dyA + dzA * dzA);
            float dxB = axB - p.x, dyB = ayB - p.y, dzB = azB - p.z;
            mnB = fminf(mnB, dxB * dxB + dyB * dyB + dzB * dzB);
        }
        sm.cd.pm[wid][lane] = mnA;
        sm.cd.pm[wid][64 + lane] = mnB;
        __syncthreads();
        if (tid < 128) {
            double v = (double)fminf(fminf(sm.cd.pm[0][tid], sm.cd.pm[1][tid]),
                                     fminf(sm.cd.pm[2][tid], sm.cd.pm[3][tid]));
            for (int off = 32; off; off >>= 1) v += __shfl_down(v, off, 64);
            if (lane == 0) atomicAdd(acc + z, v);
        }
    } else {
        // ========== repulsion: 4 waves x 512-pt chunks, 64 rows/block ==========
        int r = bid - 264;
        int b = r >> 5;
        int xb = r & 31;
        const float* pp = pred + (size_t)b * NN * 3;
        for (int j = tid; j < NN; j += 256) {
            sm.rep.sP[j] = make_float4(pp[j * 3 + 0], pp[j * 3 + 1], pp[j * 3 + 2], 0.0f);
        }
        int row = xb * 64 + lane;
        __syncthreads();
        float4 q = sm.rep.sP[row];
        float t0 = 1e30f, t1 = 1e30f, t2 = 1e30f, t3 = 1e30f, t4 = 1e30f;
        int j0 = wid * 512;
#pragma unroll 8
        for (int jj = 0; jj < 512; jj++) {
            float4 p = sm.rep.sP[j0 + jj];
            float dx = q.x - p.x, dy = q.y - p.y, dz = q.z - p.z;
            ins5(dx * dx + dy * dy + dz * dz, t0, t1, t2, t3, t4);
        }
        sm.rep.pm[wid][lane][0] = t0; sm.rep.pm[wid][lane][1] = t1;
        sm.rep.pm[wid][lane][2] = t2; sm.rep.pm[wid][lane][3] = t3;
        sm.rep.pm[wid][lane][4] = t4;
        __syncthreads();
        double v = 0.0;
        if (tid < 64) {
            t0 = sm.rep.pm[0][lane][0]; t1 = sm.rep.pm[0][lane][1]; t2 = sm.rep.pm[0][lane][2];
            t3 = sm.rep.pm[0][lane][3]; t4 = sm.rep.pm[0][lane][4];
#pragma unroll
            for (int w = 1; w < 4; w++) {
#pragma unroll
                for (int k = 0; k < 5; k++) ins5(sm.rep.pm[w][lane][k], t0, t1, t2, t3, t4);
            }
            float s = fmaxf(H_REP - t1, 0.f) + fmaxf(H_REP - t2, 0.f) +
                      fmaxf(H_REP - t3, 0.f) + fmaxf(H_REP - t4, 0.f);
            v = (double)s;
            for (int off = 32; off; off >>= 1) v += __shfl_down(v, off, 64);
            if (tid == 0) atomicAdd(acc + 2, v);
        }
    }
}

// ---------------- ball query, all 5 radii fused (z = pi) ----------------
__global__ __launch_bounds__(64) void k_ball(const float* __restrict__ pcd,
                                             const int* __restrict__ fidx,
                                             int* __restrict__ gidx) {
    int c = blockIdx.x;
    int b = blockIdx.y;
    int pi = blockIdx.z;
    int ns = c_ns[pi];
    double rd = sqrt(c_p[pi]);
    float r2 = (float)(rd * rd);
    int lane = threadIdx.x;
    const float* pp = pcd + (size_t)b * NN * 3;
    int ci = fidx[b * NPOINT + c];
    float cx = pp[ci * 3 + 0], cy = pp[ci * 3 + 1], cz = pp[ci * 3 + 2];
    float sc = cx * cx + cy * cy + cz * cz;
    int* out = gidx + c_goff[pi] + ((size_t)b * NPOINT + c) * ns;
    int cnt = 0;
    int first = 0;
    for (int j0 = 0; j0 < NN && cnt < ns; j0 += 64) {
        int j = j0 + lane;
        float x = pp[j * 3 + 0], y = pp[j * 3 + 1], z = pp[j * 3 + 2];
        float sj = x * x + y * y + z * z;
        float d2 = fmaxf(sc + sj - 2.0f * (cx * x + cy * y + cz * z), 0.0f);
        bool pred = d2 < r2;
        unsigned long long mask = __ballot(pred);
        if (cnt == 0 && mask != 0ull) first = j0 + (int)__builtin_ctzll(mask);
        if (pred) {
            int pos = cnt + (int)__popcll(mask & ((1ull << lane) - 1ull));
            if (pos < ns) out[pos] = j;
        }
        cnt += (int)__popcll(mask);
    }
    if (cnt < ns) {
        for (int s = cnt + lane; s < ns; s += 64) out[s] = first;
    }
}

// ---------------- kNN-2, all 5 fused: 2 rows/lane, 4 waves x M/4 chunks ----------------
__global__ __launch_bounds__(256) void k_uknn(const float* __restrict__ pcd,
                                              const int* __restrict__ gidx,
                                              double* __restrict__ acc) {
    int pi = blockIdx.z;
    int b = blockIdx.y;
    int ns = c_ns[pi];
    int M = NPOINT * ns;  // 816..2448, divisible by 4
    if (blockIdx.x * 128 >= M) return;
    __shared__ float4 sP[2448];  // ~39 KB
    __shared__ float pm1[4][128], pm2[4][128];
    const float* pp = pcd + (size_t)b * NN * 3;
    const int* gb = gidx + c_goff[pi] + (size_t)b * NPOINT * ns;
    for (int g = threadIdx.x; g < M; g += 256) {
        int id = gb[g];
        sP[g] = make_float4(pp[id * 3 + 0], pp[id * 3 + 1], pp[id * 3 + 2], 0.0f);
    }
    int lane = threadIdx.x & 63, wid = threadIdx.x >> 6;
    int rowA = blockIdx.x * 128 + lane;
    int rowB = rowA + 64;
    __syncthreads();
    float4 qA = (rowA < M) ? sP[rowA] : make_float4(0.f, 0.f, 0.f, 0.f);
    float4 qB = (rowB < M) ? sP[rowB] : make_float4(0.f, 0.f, 0.f, 0.f);
    float m1A = 1e30f, m2A = 1e30f, m1B = 1e30f, m2B = 1e30f;
    int Mq = M >> 2;
    int j0 = wid * Mq;
#pragma unroll 4
    for (int jj = 0; jj < Mq; jj++) {
        float4 p = sP[j0 + jj];
        // direct formula: exact 0 for bit-identical duplicates (padding!)
        float dxA = qA.x - p.x, dyA = qA.y - p.y, dzA = qA.z - p.z;
        float dA = dxA * dxA + dyA * dyA + dzA * dzA;
        float loA = fminf(m1A, dA), hiA = fmaxf(m1A, dA);
        m1A = loA; m2A = fminf(m2A, hiA);
        float dxB = qB.x - p.x, dyB = qB.y - p.y, dzB = qB.z - p.z;
        float dB = dxB * dxB + dyB * dyB + dzB * dzB;
        float loB = fminf(m1B, dB), hiB = fmaxf(m1B, dB);
        m1B = loB; m2B = fminf(m2B, hiB);
    }
    pm1[wid][lane] = m1A; pm2[wid][lane] = m2A;
    pm1[wid][64 + lane] = m1B; pm2[wid][64 + lane] = m2B;
    __syncthreads();
    if (threadIdx.x < 128) {
        int row = blockIdx.x * 128 + threadIdx.x;
        double v = 0.0;
        if (row < M) {
            float a1 = pm1[0][threadIdx.x], a2 = pm2[0][threadIdx.x];
#pragma unroll
            for (int w = 1; w < 4; w++) {
                float b1 = pm1[w][threadIdx.x], b2 = pm2[w][threadIdx.x];
                float n1 = fminf(a1, b1);
                float n2 = fminf(fmaxf(a1, b1), fminf(a2, b2));
                a1 = n1; a2 = n2;
            }
            v = (double)(sqrtf(a2) + 1e-8f);
        }
        for (int off = 32; off; off >>= 1) v += __shfl_down(v, off, 64);
        if (lane == 0) atomicAdd(acc + 3 + pi * 8 + b, v);
    }
}

// ---------------- finalize (one wave; lanes 0..39 = (pi,b) terms) ----------------
__global__ __launch_bounds__(64) void k_final(const double* __restrict__ acc,
                                              const float* __restrict__ radius,
                                              float* __restrict__ out) {
    int lane = threadIdx.x;
    double v = 0.0;
    if (lane < 40) {
        int pi = lane >> 3;
        int b = lane & 7;
        double p = c_p[pi];
        int M = NPOINT * c_ns[pi];
        double disk_area = M_PI * 1.0 / (double)NN;
        double e = sqrt(disk_area);
        double m = acc[3 + pi * 8 + b] / (double)M;
        double d = m - e;
        double w = (p * 100.0) * (p * 100.0);
        v = d * d / (e + 1e-8) * w / 40.0;  // /(8 batches * 5 percentages)
    }
    for (int off = 32; off; off >>= 1) v += __shfl_down(v, off, 64);
    if (lane == 0) {
        double cd = (0.8 * acc[0] + 0.2 * acc[1]) / ((double)BB * NN) / (double)radius[0];
        double rep = acc[2] / ((double)BB * NN * 4.0);
        out[0] = (float)(cd + rep + v);
    }
}

extern "C" void kernel_launch(void* const* d_in, const int* in_sizes, int n_in,
                              void* d_out, int out_size, void* d_ws, size_t ws_size,
                              hipStream_t stream) {
    const float* pred = (const float*)d_in[0];
    const float* gt = (const float*)d_in[1];
    const float* radius = (const float*)d_in[2];
    float* out = (float*)d_out;

    double* acc = (double*)d_ws;             // 48 doubles: 0=for 1=bac 2=rep 3..42=uni[5][8]
    int* fidx = (int*)(acc + 48);            // 8*102 ints
    int* gidx = (int*)(fidx + BB * NPOINT);  // 65280 ints (all 5 pi regions)

    hipMemsetAsync(acc, 0, 48 * sizeof(double), stream);
    hipLaunchKernelGGL(k_phase1, dim3(520), dim3(256), 0, stream, pred, gt, fidx, acc);
    hipLaunchKernelGGL(k_ball, dim3(NPOINT, BB, 5), dim3(64), 0, stream, pred, fidx, gidx);
    hipLaunchKernelGGL(k_uknn, dim3(20, BB, 5), dim3(256), 0, stream, pred, gidx, acc);
    hipLaunchKernelGGL(k_final, dim3(1), dim3(64), 0, stream, acc, radius, out);
}

// Round 7
// 156.799 us; speedup vs baseline: 9.4642x; 1.0539x over previous
//
#include <hip/hip_runtime.h>
#include <math.h>

#define BB 8
#define NN 2048
#define NPOINT 102
#define H_REP 0.0005f

__device__ const int    c_ns[5]   = {8, 12, 16, 20, 24};
__device__ const double c_p[5]    = {0.004, 0.006, 0.008, 0.01, 0.012};
__device__ const int    c_goff[5] = {0, 6528, 16320, 29376, 45696};  // ints; 816*ns prefix

// branchless sorted-5 insert (keeps t0<=t1<=t2<=t3<=t4)
__device__ inline void ins5(float c, float& t0, float& t1, float& t2, float& t3, float& t4) {
    float lo;
    lo = fminf(t0, c); c = fmaxf(t0, c); t0 = lo;
    lo = fminf(t1, c); c = fmaxf(t1, c); t1 = lo;
    lo = fminf(t2, c); c = fmaxf(t2, c); t2 = lo;
    lo = fminf(t3, c); c = fmaxf(t3, c); t3 = lo;
    t4 = fminf(t4, c);
}

// argmax pair combine: max value, tie -> smaller index (matches jnp.argmax)
__device__ inline void pcomb(float v2, int i2, float& v, int& i) {
    bool take = (v2 > v) || (v2 == v && i2 < i);
    v = take ? v2 : v;
    i = take ? i2 : i;
}

union SMem {
    struct { float4 sB[NN]; float pm[4][128]; } cd;        // 32K + 2K
    struct { float4 sP[NN]; float pm[4][64][5]; } rep;     // 32K + 5K
    struct { float4 sP[NN]; float2 sl[2][4]; } fps;        // 32K + 64B
};

// ---------------- phase1: blocks [0,8)=fps  [8,264)=cd  [264,520)=rep ----------------
__global__ __launch_bounds__(256, 2) void k_phase1(const float* __restrict__ pred,
                                                   const float* __restrict__ gt,
                                                   int* __restrict__ fidx,
                                                   double* __restrict__ acc) {
    __shared__ SMem sm;
    int bid = blockIdx.x;
    int tid = threadIdx.x;
    int lane = tid & 63, wid = tid >> 6;

    if (bid < 8) {
        // ========== FPS: 4 waves x 8 pts/lane (fits VGPRs - NO spill), DPP argmax,
        //             single-barrier double-buffered cross-wave merge ==========
        __builtin_amdgcn_s_setprio(1);
        int b = bid;
        const float* pp = pred + (size_t)b * NN * 3;
        float px[8], py[8], pz[8], dist[8];
#pragma unroll
        for (int k = 0; k < 8; k++) {
            int i = (wid << 9) + (k << 6) + lane;  // wave wid owns [wid*512, wid*512+512)
            float x = pp[i * 3 + 0], y = pp[i * 3 + 1], z = pp[i * 3 + 2];
            px[k] = x; py[k] = y; pz[k] = z; dist[k] = 1e10f;
            sm.fps.sP[i] = make_float4(x, y, z, 0.0f);
        }
        if (tid == 0) fidx[b * NPOINT + 0] = 0;
        __syncthreads();
        int last = 0;
#pragma unroll 1
        for (int step = 1; step < NPOINT; ++step) {
            float4 lp = sm.fps.sP[last];
            float bv = -1.0f;
            int bi = 0;
#pragma unroll
            for (int k = 0; k < 8; k++) {
                float dx = px[k] - lp.x, dy = py[k] - lp.y, dz = pz[k] - lp.z;
                float nd = fminf(dist[k], dx * dx + dy * dy + dz * dz);
                dist[k] = nd;
                bool better = nd > bv;  // ascending k -> first-max kept (min global idx)
                bv = better ? nd : bv;
                bi = better ? ((wid << 9) + (k << 6) + lane) : bi;
            }
            // wave-64 argmax in-register: row_ror 1,2,4,8 then bcast15, bcast31.
            // pcomb is idempotent (max, tie->min idx) so bcast double-combines are safe.
            {
                float v2; int i2;
#define DPPC(CTRL)                                                                          \
                v2 = __int_as_float(__builtin_amdgcn_update_dpp(                            \
                        __float_as_int(bv), __float_as_int(bv), CTRL, 0xF, 0xF, false));    \
                i2 = __builtin_amdgcn_update_dpp(bi, bi, CTRL, 0xF, 0xF, false);            \
                pcomb(v2, i2, bv, bi);
                DPPC(0x121)  // row_ror:1
                DPPC(0x122)  // row_ror:2
                DPPC(0x124)  // row_ror:4
                DPPC(0x128)  // row_ror:8
                DPPC(0x142)  // row_bcast15
                DPPC(0x143)  // row_bcast31
#undef DPPC
            }
            int pb = step & 1;
            if (lane == 63) sm.fps.sl[pb][wid] = make_float2(bv, __int_as_float(bi));
            __syncthreads();
            // all threads redundantly merge the 4 wave winners (broadcast LDS reads)
            float fv = -2.0f;
            int fi = 0;
#pragma unroll
            for (int w = 0; w < 4; w++) {  // ascending wave -> disjoint ascending idx ranges
                float2 s = sm.fps.sl[pb][w];
                pcomb(s.x, __float_as_int(s.y), fv, fi);
            }
            if (tid == 0) fidx[b * NPOINT + step] = fi;
            last = fi;  // uniform across block; no second barrier (double-buffered slots)
        }
    } else if (bid < 264) {
        // ========== chamfer: 2 rows/lane (128 rows/block), 4 waves x 512-pt chunks ==========
        int r = bid - 8;
        int z = r >> 7;
        int b = (r >> 4) & 7;
        int xb = r & 15;
        const float* A = z ? pred : gt;
        const float* Bp = z ? gt : pred;
        const float* bb = Bp + (size_t)b * NN * 3;
        for (int j = tid; j < NN; j += 256) {
            sm.cd.sB[j] = make_float4(bb[j * 3 + 0], bb[j * 3 + 1], bb[j * 3 + 2], 0.0f);
        }
        int rowA = xb * 128 + lane;
        int rowB = rowA + 64;
        const float* aA = A + ((size_t)b * NN + rowA) * 3;
        const float* aB = A + ((size_t)b * NN + rowB) * 3;
        float axA = aA[0], ayA = aA[1], azA = aA[2];
        float axB = aB[0], ayB = aB[1], azB = aB[2];
        __syncthreads();
        float mnA = 1e30f, mnB = 1e30f;
        int j0 = wid * 512;
#pragma unroll 8
        for (int jj = 0; jj < 512; jj++) {
            float4 p = sm.cd.sB[j0 + jj];
            float dxA = axA - p.x, dyA = ayA - p.y, dzA = azA - p.z;
            mnA = fminf(mnA, dxA * dxA + dyA * dyA + dzA * dzA);
            float dxB = axB - p.x, dyB = ayB - p.y, dzB = azB - p.z;
            mnB = fminf(mnB, dxB * dxB + dyB * dyB + dzB * dzB);
        }
        sm.cd.pm[wid][lane] = mnA;
        sm.cd.pm[wid][64 + lane] = mnB;
        __syncthreads();
        if (tid < 128) {
            double v = (double)fminf(fminf(sm.cd.pm[0][tid], sm.cd.pm[1][tid]),
                                     fminf(sm.cd.pm[2][tid], sm.cd.pm[3][tid]));
            for (int off = 32; off; off >>= 1) v += __shfl_down(v, off, 64);
            if (lane == 0) atomicAdd(acc + z, v);
        }
    } else {
        // ========== repulsion: 4 waves x 512-pt chunks, 64 rows/block ==========
        int r = bid - 264;
        int b = r >> 5;
        int xb = r & 31;
        const float* pp = pred + (size_t)b * NN * 3;
        for (int j = tid; j < NN; j += 256) {
            sm.rep.sP[j] = make_float4(pp[j * 3 + 0], pp[j * 3 + 1], pp[j * 3 + 2], 0.0f);
        }
        int row = xb * 64 + lane;
        __syncthreads();
        float4 q = sm.rep.sP[row];
        float t0 = 1e30f, t1 = 1e30f, t2 = 1e30f, t3 = 1e30f, t4 = 1e30f;
        int j0 = wid * 512;
#pragma unroll 8
        for (int jj = 0; jj < 512; jj++) {
            float4 p = sm.rep.sP[j0 + jj];
            float dx = q.x - p.x, dy = q.y - p.y, dz = q.z - p.z;
            ins5(dx * dx + dy * dy + dz * dz, t0, t1, t2, t3, t4);
        }
        sm.rep.pm[wid][lane][0] = t0; sm.rep.pm[wid][lane][1] = t1;
        sm.rep.pm[wid][lane][2] = t2; sm.rep.pm[wid][lane][3] = t3;
        sm.rep.pm[wid][lane][4] = t4;
        __syncthreads();
        double v = 0.0;
        if (tid < 64) {
            t0 = sm.rep.pm[0][lane][0]; t1 = sm.rep.pm[0][lane][1]; t2 = sm.rep.pm[0][lane][2];
            t3 = sm.rep.pm[0][lane][3]; t4 = sm.rep.pm[0][lane][4];
#pragma unroll
            for (int w = 1; w < 4; w++) {
#pragma unroll
                for (int k = 0; k < 5; k++) ins5(sm.rep.pm[w][lane][k], t0, t1, t2, t3, t4);
            }
            float s = fmaxf(H_REP - t1, 0.f) + fmaxf(H_REP - t2, 0.f) +
                      fmaxf(H_REP - t3, 0.f) + fmaxf(H_REP - t4, 0.f);
            v = (double)s;
            for (int off = 32; off; off >>= 1) v += __shfl_down(v, off, 64);
            if (tid == 0) atomicAdd(acc + 2, v);
        }
    }
}

// ---------------- ball query, all 5 radii fused (z = pi) ----------------
__global__ __launch_bounds__(64) void k_ball(const float* __restrict__ pcd,
                                             const int* __restrict__ fidx,
                                             int* __restrict__ gidx) {
    int c = blockIdx.x;
    int b = blockIdx.y;
    int pi = blockIdx.z;
    int ns = c_ns[pi];
    double rd = sqrt(c_p[pi]);
    float r2 = (float)(rd * rd);
    int lane = threadIdx.x;
    const float* pp = pcd + (size_t)b * NN * 3;
    int ci = fidx[b * NPOINT + c];
    float cx = pp[ci * 3 + 0], cy = pp[ci * 3 + 1], cz = pp[ci * 3 + 2];
    float sc = cx * cx + cy * cy + cz * cz;
    int* out = gidx + c_goff[pi] + ((size_t)b * NPOINT + c) * ns;
    int cnt = 0;
    int first = 0;
    for (int j0 = 0; j0 < NN && cnt < ns; j0 += 64) {
        int j = j0 + lane;
        float x = pp[j * 3 + 0], y = pp[j * 3 + 1], z = pp[j * 3 + 2];
        float sj = x * x + y * y + z * z;
        float d2 = fmaxf(sc + sj - 2.0f * (cx * x + cy * y + cz * z), 0.0f);
        bool pred = d2 < r2;
        unsigned long long mask = __ballot(pred);
        if (cnt == 0 && mask != 0ull) first = j0 + (int)__builtin_ctzll(mask);
        if (pred) {
            int pos = cnt + (int)__popcll(mask & ((1ull << lane) - 1ull));
            if (pos < ns) out[pos] = j;
        }
        cnt += (int)__popcll(mask);
    }
    if (cnt < ns) {
        for (int s = cnt + lane; s < ns; s += 64) out[s] = first;
    }
}

// ---------------- kNN-2, all 5 fused: 2 rows/lane, 4 waves x M/4 chunks ----------------
__global__ __launch_bounds__(256) void k_uknn(const float* __restrict__ pcd,
                                              const int* __restrict__ gidx,
                                              double* __restrict__ acc) {
    int pi = blockIdx.z;
    int b = blockIdx.y;
    int ns = c_ns[pi];
    int M = NPOINT * ns;  // 816..2448, divisible by 4
    if (blockIdx.x * 128 >= M) return;
    __shared__ float4 sP[2448];  // ~39 KB
    __shared__ float pm1[4][128], pm2[4][128];
    const float* pp = pcd + (size_t)b * NN * 3;
    const int* gb = gidx + c_goff[pi] + (size_t)b * NPOINT * ns;
    for (int g = threadIdx.x; g < M; g += 256) {
        int id = gb[g];
        sP[g] = make_float4(pp[id * 3 + 0], pp[id * 3 + 1], pp[id * 3 + 2], 0.0f);
    }
    int lane = threadIdx.x & 63, wid = threadIdx.x >> 6;
    int rowA = blockIdx.x * 128 + lane;
    int rowB = rowA + 64;
    __syncthreads();
    float4 qA = (rowA < M) ? sP[rowA] : make_float4(0.f, 0.f, 0.f, 0.f);
    float4 qB = (rowB < M) ? sP[rowB] : make_float4(0.f, 0.f, 0.f, 0.f);
    float m1A = 1e30f, m2A = 1e30f, m1B = 1e30f, m2B = 1e30f;
    int Mq = M >> 2;
    int j0 = wid * Mq;
#pragma unroll 4
    for (int jj = 0; jj < Mq; jj++) {
        float4 p = sP[j0 + jj];
        // direct formula: exact 0 for bit-identical duplicates (padding!)
        float dxA = qA.x - p.x, dyA = qA.y - p.y, dzA = qA.z - p.z;
        float dA = dxA * dxA + dyA * dyA + dzA * dzA;
        float loA = fminf(m1A, dA), hiA = fmaxf(m1A, dA);
        m1A = loA; m2A = fminf(m2A, hiA);
        float dxB = qB.x - p.x, dyB = qB.y - p.y, dzB = qB.z - p.z;
        float dB = dxB * dxB + dyB * dyB + dzB * dzB;
        float loB = fminf(m1B, dB), hiB = fmaxf(m1B, dB);
        m1B = loB; m2B = fminf(m2B, hiB);
    }
    pm1[wid][lane] = m1A; pm2[wid][lane] = m2A;
    pm1[wid][64 + lane] = m1B; pm2[wid][64 + lane] = m2B;
    __syncthreads();
    if (threadIdx.x < 128) {
        int row = blockIdx.x * 128 + threadIdx.x;
        double v = 0.0;
        if (row < M) {
            float a1 = pm1[0][threadIdx.x], a2 = pm2[0][threadIdx.x];
#pragma unroll
            for (int w = 1; w < 4; w++) {
                float b1 = pm1[w][threadIdx.x], b2 = pm2[w][threadIdx.x];
                float n1 = fminf(a1, b1);
                float n2 = fminf(fmaxf(a1, b1), fminf(a2, b2));
                a1 = n1; a2 = n2;
            }
            v = (double)(sqrtf(a2) + 1e-8f);
        }
        for (int off = 32; off; off >>= 1) v += __shfl_down(v, off, 64);
        if (lane == 0) atomicAdd(acc + 3 + pi * 8 + b, v);
    }
}

// ---------------- finalize (one wave; lanes 0..39 = (pi,b) terms) ----------------
__global__ __launch_bounds__(64) void k_final(const double* __restrict__ acc,
                                              const float* __restrict__ radius,
                                              float* __restrict__ out) {
    int lane = threadIdx.x;
    double v = 0.0;
    if (lane < 40) {
        int pi = lane >> 3;
        int b = lane & 7;
        double p = c_p[pi];
        int M = NPOINT * c_ns[pi];
        double disk_area = M_PI * 1.0 / (double)NN;
        double e = sqrt(disk_area);
        double m = acc[3 + pi * 8 + b] / (double)M;
        double d = m - e;
        double w = (p * 100.0) * (p * 100.0);
        v = d * d / (e + 1e-8) * w / 40.0;  // /(8 batches * 5 percentages)
    }
    for (int off = 32; off; off >>= 1) v += __shfl_down(v, off, 64);
    if (lane == 0) {
        double cd = (0.8 * acc[0] + 0.2 * acc[1]) / ((double)BB * NN) / (double)radius[0];
        double rep = acc[2] / ((double)BB * NN * 4.0);
        out[0] = (float)(cd + rep + v);
    }
}

extern "C" void kernel_launch(void* const* d_in, const int* in_sizes, int n_in,
                              void* d_out, int out_size, void* d_ws, size_t ws_size,
                              hipStream_t stream) {
    const float* pred = (const float*)d_in[0];
    const float* gt = (const float*)d_in[1];
    const float* radius = (const float*)d_in[2];
    float* out = (float*)d_out;

    double* acc = (double*)d_ws;             // 48 doubles: 0=for 1=bac 2=rep 3..42=uni[5][8]
    int* fidx = (int*)(acc + 48);            // 8*102 ints
    int* gidx = (int*)(fidx + BB * NPOINT);  // 65280 ints (all 5 pi regions)

    hipMemsetAsync(acc, 0, 48 * sizeof(double), stream);
    hipLaunchKernelGGL(k_phase1, dim3(520), dim3(256), 0, stream, pred, gt, fidx, acc);
    hipLaunchKernelGGL(k_ball, dim3(NPOINT, BB, 5), dim3(64), 0, stream, pred, fidx, gidx);
    hipLaunchKernelGGL(k_uknn, dim3(20, BB, 5), dim3(256), 0, stream, pred, gidx, acc);
    hipLaunchKernelGGL(k_final, dim3(1), dim3(64), 0, stream, acc, radius, out);
}